// Round 1
// baseline (689.374 us; speedup 1.0000x reference)
//
#include <hip/hip_runtime.h>

#define NODES 100000
#define KNN 6

// Fused PointNetConv layer:
//   per edge e (grouped 6 consecutive per node): in = [x[src[e]], pos[src]-pos[node]]
//   hid = relu(in @ Wa + ba); o = hid @ Wb + bb
//   out[node] = relu(max over the node's 6 edges of o)
//
// Block = NB nodes (M = 6*NB edges). Thread tile = 6 edges (one node) x 8 outputs.
// At (transposed input tile) and Ht (transposed hidden tile) live in LDS; weights
// are read from global (small, cache-resident).
template <int C_X, int HID, int NB, int TX>
__global__ __launch_bounds__(NB * TX) void pnconv(
    const float* __restrict__ x,    // [NODES][C_X] node features (pos for layer 1)
    const float* __restrict__ pos,  // [NODES][3]
    const int* __restrict__ ei,     // [2][E]; row 0 = src
    const float* __restrict__ Wa, const float* __restrict__ ba,
    const float* __restrict__ Wb, const float* __restrict__ bb,
    float* __restrict__ out)        // [NODES][HID]
{
    constexpr int CIN = C_X + 3;
    constexpr int M = NB * KNN;
    constexpr int MPAD = M + 2;   // even stride, avoids mod-32 alignment of rows
    constexpr int TY = NB;
    constexpr int NT = TX * TY;
    static_assert(TX * 8 == HID, "8 outputs per thread must cover HID");

    __shared__ float At[CIN * MPAD];
    __shared__ float Ht[HID * MPAD];
    __shared__ int srcs[M];

    const int tid = threadIdx.x;
    const int node0 = blockIdx.x * NB;
    const long e0 = (long)node0 * KNN;

    // ---- stage 0: src indices + relative-position rows (+ x rows for layer 1)
    for (int e = tid; e < M; e += NT) {
        const int s = ei[e0 + e];
        srcs[e] = s;
        const int node = node0 + e / KNN;
        const float sx = pos[3 * s + 0];
        const float sy = pos[3 * s + 1];
        const float sz = pos[3 * s + 2];
        At[(C_X + 0) * MPAD + e] = sx - pos[3 * node + 0];
        At[(C_X + 1) * MPAD + e] = sy - pos[3 * node + 1];
        At[(C_X + 2) * MPAD + e] = sz - pos[3 * node + 2];
        if constexpr (C_X == 3) {
            At[0 * MPAD + e] = sx;
            At[1 * MPAD + e] = sy;
            At[2 * MPAD + e] = sz;
        }
    }
    __syncthreads();

    // ---- stage 1: gather x[src] into At (transposed), float4-vectorized
    if constexpr (C_X % 4 == 0) {
        constexpr int C4 = C_X / 4;
        for (int idx = tid; idx < M * C4; idx += NT) {
            const int e = idx / C4;
            const int c4 = idx - e * C4;
            const int s = srcs[e];
            const float4 v = *(const float4*)(x + (size_t)s * C_X + 4 * c4);
            At[(4 * c4 + 0) * MPAD + e] = v.x;
            At[(4 * c4 + 1) * MPAD + e] = v.y;
            At[(4 * c4 + 2) * MPAD + e] = v.z;
            At[(4 * c4 + 3) * MPAD + e] = v.w;
        }
        __syncthreads();
    }

    const int tx = tid % TX;
    const int ty = tid / TX;      // ty == node-within-block; owns 6 edges
    const int m0 = ty * KNN;
    const int n0 = tx * 8;

    float acc[KNN][8];

    // ---- GEMM1: hid = relu(A @ Wa + ba)
    {
        const float4 q0 = *(const float4*)(ba + n0);
        const float4 q1 = *(const float4*)(ba + n0 + 4);
#pragma unroll
        for (int m = 0; m < KNN; m++) {
            acc[m][0] = q0.x; acc[m][1] = q0.y; acc[m][2] = q0.z; acc[m][3] = q0.w;
            acc[m][4] = q1.x; acc[m][5] = q1.y; acc[m][6] = q1.z; acc[m][7] = q1.w;
        }
    }
#pragma unroll 2
    for (int k = 0; k < CIN; k++) {
        const float4 w0 = *(const float4*)(Wa + k * HID + n0);
        const float4 w1 = *(const float4*)(Wa + k * HID + n0 + 4);
        const float wv[8] = {w0.x, w0.y, w0.z, w0.w, w1.x, w1.y, w1.z, w1.w};
        float a[KNN];
#pragma unroll
        for (int m = 0; m < KNN; m += 2) {
            const float2 t = *(const float2*)&At[k * MPAD + m0 + m];
            a[m] = t.x;
            a[m + 1] = t.y;
        }
#pragma unroll
        for (int m = 0; m < KNN; m++)
#pragma unroll
            for (int n = 0; n < 8; n++)
                acc[m][n] = fmaf(a[m], wv[n], acc[m][n]);
    }
    // relu + write transposed hidden tile
#pragma unroll
    for (int n = 0; n < 8; n++) {
#pragma unroll
        for (int m = 0; m < KNN; m += 2) {
            float2 t;
            t.x = fmaxf(acc[m][n], 0.f);
            t.y = fmaxf(acc[m + 1][n], 0.f);
            *(float2*)&Ht[(n0 + n) * MPAD + m0 + m] = t;
        }
    }
    __syncthreads();

    // ---- GEMM2: o = hid @ Wb + bb
    {
        const float4 q0 = *(const float4*)(bb + n0);
        const float4 q1 = *(const float4*)(bb + n0 + 4);
#pragma unroll
        for (int m = 0; m < KNN; m++) {
            acc[m][0] = q0.x; acc[m][1] = q0.y; acc[m][2] = q0.z; acc[m][3] = q0.w;
            acc[m][4] = q1.x; acc[m][5] = q1.y; acc[m][6] = q1.z; acc[m][7] = q1.w;
        }
    }
#pragma unroll 2
    for (int k = 0; k < HID; k++) {
        const float4 w0 = *(const float4*)(Wb + k * HID + n0);
        const float4 w1 = *(const float4*)(Wb + k * HID + n0 + 4);
        const float wv[8] = {w0.x, w0.y, w0.z, w0.w, w1.x, w1.y, w1.z, w1.w};
        float a[KNN];
#pragma unroll
        for (int m = 0; m < KNN; m += 2) {
            const float2 t = *(const float2*)&Ht[k * MPAD + m0 + m];
            a[m] = t.x;
            a[m + 1] = t.y;
        }
#pragma unroll
        for (int m = 0; m < KNN; m++)
#pragma unroll
            for (int n = 0; n < 8; n++)
                acc[m][n] = fmaf(a[m], wv[n], acc[m][n]);
    }

    // ---- segment max over this node's 6 edges + outer relu, coalesced store
    float res[8];
#pragma unroll
    for (int n = 0; n < 8; n++) {
        float v = acc[0][n];
#pragma unroll
        for (int m = 1; m < KNN; m++) v = fmaxf(v, acc[m][n]);
        res[n] = fmaxf(v, 0.f);
    }
    const int node = node0 + ty;
    float4 r0, r1;
    r0.x = res[0]; r0.y = res[1]; r0.z = res[2]; r0.w = res[3];
    r1.x = res[4]; r1.y = res[5]; r1.z = res[6]; r1.w = res[7];
    *(float4*)(out + (size_t)node * HID + n0) = r0;
    *(float4*)(out + (size_t)node * HID + n0 + 4) = r1;
}

extern "C" void kernel_launch(void* const* d_in, const int* in_sizes, int n_in,
                              void* d_out, int out_size, void* d_ws, size_t ws_size,
                              hipStream_t stream) {
    const float* pos = (const float*)d_in[0];
    const int* ei = (const int*)d_in[1];
    const float* W1a = (const float*)d_in[2];
    const float* b1a = (const float*)d_in[3];
    const float* W1b = (const float*)d_in[4];
    const float* b1b = (const float*)d_in[5];
    const float* W2a = (const float*)d_in[6];
    const float* b2a = (const float*)d_in[7];
    const float* W2b = (const float*)d_in[8];
    const float* b2b = (const float*)d_in[9];
    const float* W3a = (const float*)d_in[10];
    const float* b3a = (const float*)d_in[11];
    const float* W3b = (const float*)d_in[12];
    const float* b3b = (const float*)d_in[13];

    float* h1 = (float*)d_ws;                       // [NODES][32]
    float* h2 = h1 + (size_t)NODES * 32;            // [NODES][64]
    float* outp = (float*)d_out;                    // [NODES][128]

    // Layer 1: CIN=6, HID=32; NB=32 nodes/block, 128 threads
    pnconv<3, 32, 32, 4><<<NODES / 32, 128, 0, stream>>>(
        pos, pos, ei, W1a, b1a, W1b, b1b, h1);
    // Layer 2: CIN=35, HID=64; NB=16 nodes/block, 128 threads
    pnconv<32, 64, 16, 8><<<NODES / 16, 128, 0, stream>>>(
        h1, pos, ei, W2a, b2a, W2b, b2b, h2);
    // Layer 3: CIN=67, HID=128; NB=8 nodes/block, 128 threads
    pnconv<64, 128, 8, 16><<<NODES / 8, 128, 0, stream>>>(
        h2, pos, ei, W3a, b3a, W3b, b3b, outp);
}

// Round 2
// 572.164 us; speedup vs baseline: 1.2049x; 1.2049x over previous
//
#include <hip/hip_runtime.h>

#define NODES 100000
#define KNN 6

// Fused PointNetConv layer:
//   per edge e (grouped 6 consecutive per node): in = [x[src[e]], pos[src]-pos[node]]
//   hid = relu(in @ Wa + ba); o = hid @ Wb + bb
//   out[node] = relu(max over the node's 6 edges of o)
//
// Block = NB nodes (M = 6*NB edges). Thread tile = 6 edges (one node) x 8 outputs.
// At (transposed input tile) and Ht (transposed hidden tile) live in LDS with odd
// leading stride (MPAD = M+1) so the Ht-write tx-stride hits 16 banks not 2.
// The k-loops are software-pipelined: weight float4s + A-values for the NEXT
// group of 4 k-steps are loaded into a ping-pong register set before the current
// group's 192 FMAs execute, hiding L2 latency at 2 waves/SIMD.
template <int C_X, int HID, int NB, int TX>
__global__ __launch_bounds__(NB * TX, 2) void pnconv(
    const float* __restrict__ x,    // [NODES][C_X] node features (pos for layer 1)
    const float* __restrict__ pos,  // [NODES][3]
    const int* __restrict__ ei,     // [2][E]; row 0 = src
    const float* __restrict__ Wa, const float* __restrict__ ba,
    const float* __restrict__ Wb, const float* __restrict__ bb,
    float* __restrict__ out)        // [NODES][HID]
{
    constexpr int CIN = C_X + 3;
    constexpr int M = NB * KNN;
    constexpr int MPAD = M + 1;   // ODD stride: breaks the 8*MPAD%32 bank collapse
    constexpr int TY = NB;
    constexpr int NT = TX * TY;
    static_assert(TX * 8 == HID, "8 outputs per thread must cover HID");

    __shared__ float At[CIN * MPAD];
    __shared__ float Ht[HID * MPAD];
    __shared__ int srcs[M];

    const int tid = threadIdx.x;
    const int node0 = blockIdx.x * NB;
    const long e0 = (long)node0 * KNN;

    // ---- stage 0: src indices + relative-position rows (+ x rows for layer 1)
    for (int e = tid; e < M; e += NT) {
        const int s = ei[e0 + e];
        srcs[e] = s;
        const int node = node0 + e / KNN;
        const float sx = pos[3 * s + 0];
        const float sy = pos[3 * s + 1];
        const float sz = pos[3 * s + 2];
        At[(C_X + 0) * MPAD + e] = sx - pos[3 * node + 0];
        At[(C_X + 1) * MPAD + e] = sy - pos[3 * node + 1];
        At[(C_X + 2) * MPAD + e] = sz - pos[3 * node + 2];
        if constexpr (C_X == 3) {
            At[0 * MPAD + e] = sx;
            At[1 * MPAD + e] = sy;
            At[2 * MPAD + e] = sz;
        }
    }
    __syncthreads();

    // ---- stage 1: gather x[src] into At (transposed), float4-vectorized loads
    if constexpr (C_X % 4 == 0) {
        constexpr int C4 = C_X / 4;
        for (int idx = tid; idx < M * C4; idx += NT) {
            const int e = idx / C4;
            const int c4 = idx - e * C4;
            const int s = srcs[e];
            const float4 v = *(const float4*)(x + (size_t)s * C_X + 4 * c4);
            At[(4 * c4 + 0) * MPAD + e] = v.x;
            At[(4 * c4 + 1) * MPAD + e] = v.y;
            At[(4 * c4 + 2) * MPAD + e] = v.z;
            At[(4 * c4 + 3) * MPAD + e] = v.w;
        }
        __syncthreads();
    }

    const int tx = tid % TX;
    const int ty = tid / TX;      // ty == node-within-block; owns 6 edges
    const int m0 = ty * KNN;
    const int n0 = tx * 8;

    float acc[KNN][8];

    // Software-pipelined GEMM over K k-steps: acc[m][n] += A[k][m0+m] * W[k][n0+n]
    auto run_gemm = [&](const float* __restrict__ W, const float* A, int K) {
        float4 wa0[4], wa1[4], wb0[4], wb1[4];
        float aa[4][KNN], ab[4][KNN];

        auto load = [&](int kb, float4* w0, float4* w1, float (*a)[KNN]) {
#pragma unroll
            for (int j = 0; j < 4; j++) {
                const float* wr = W + (size_t)(kb + j) * HID + n0;
                w0[j] = *(const float4*)wr;
                w1[j] = *(const float4*)(wr + 4);
#pragma unroll
                for (int m = 0; m < KNN; m++)
                    a[j][m] = A[(kb + j) * MPAD + m0 + m];
            }
        };
        auto comp = [&](const float4* w0, const float4* w1, const float (*a)[KNN]) {
#pragma unroll
            for (int j = 0; j < 4; j++) {
                const float wv[8] = {w0[j].x, w0[j].y, w0[j].z, w0[j].w,
                                     w1[j].x, w1[j].y, w1[j].z, w1[j].w};
#pragma unroll
                for (int m = 0; m < KNN; m++)
#pragma unroll
                    for (int n = 0; n < 8; n++)
                        acc[m][n] = fmaf(a[j][m], wv[n], acc[m][n]);
            }
        };

        const int KM = K & ~7;   // pipelined portion (multiple of 8)
        if (KM >= 8) {
            load(0, wa0, wa1, aa);
            for (int kb = 0; kb < KM; kb += 8) {
                load(kb + 4, wb0, wb1, ab);          // prefetch next group
                comp(wa0, wa1, aa);
                const int kn = (kb + 8 < KM) ? kb + 8 : kb;  // last iter: dummy (valid addrs)
                load(kn, wa0, wa1, aa);
                comp(wb0, wb1, ab);
            }
        }
        // remainder (<8 steps), unpipelined
        for (int k = KM; k < K; k++) {
            const float* wr = W + (size_t)k * HID + n0;
            const float4 w0 = *(const float4*)wr;
            const float4 w1 = *(const float4*)(wr + 4);
            const float wv[8] = {w0.x, w0.y, w0.z, w0.w, w1.x, w1.y, w1.z, w1.w};
            float a[KNN];
#pragma unroll
            for (int m = 0; m < KNN; m++) a[m] = A[k * MPAD + m0 + m];
#pragma unroll
            for (int m = 0; m < KNN; m++)
#pragma unroll
                for (int n = 0; n < 8; n++)
                    acc[m][n] = fmaf(a[m], wv[n], acc[m][n]);
        }
    };

    // ---- GEMM1: hid = relu(A @ Wa + ba)
    {
        const float4 q0 = *(const float4*)(ba + n0);
        const float4 q1 = *(const float4*)(ba + n0 + 4);
#pragma unroll
        for (int m = 0; m < KNN; m++) {
            acc[m][0] = q0.x; acc[m][1] = q0.y; acc[m][2] = q0.z; acc[m][3] = q0.w;
            acc[m][4] = q1.x; acc[m][5] = q1.y; acc[m][6] = q1.z; acc[m][7] = q1.w;
        }
    }
    run_gemm(Wa, At, CIN);

    // relu + write transposed hidden tile (b32 stores; MPAD odd → 16 banks)
#pragma unroll
    for (int n = 0; n < 8; n++)
#pragma unroll
        for (int m = 0; m < KNN; m++)
            Ht[(n0 + n) * MPAD + m0 + m] = fmaxf(acc[m][n], 0.f);
    __syncthreads();

    // ---- GEMM2: o = hid @ Wb + bb
    {
        const float4 q0 = *(const float4*)(bb + n0);
        const float4 q1 = *(const float4*)(bb + n0 + 4);
#pragma unroll
        for (int m = 0; m < KNN; m++) {
            acc[m][0] = q0.x; acc[m][1] = q0.y; acc[m][2] = q0.z; acc[m][3] = q0.w;
            acc[m][4] = q1.x; acc[m][5] = q1.y; acc[m][6] = q1.z; acc[m][7] = q1.w;
        }
    }
    run_gemm(Wb, Ht, HID);

    // ---- segment max over this node's 6 edges + outer relu, coalesced store
    float res[8];
#pragma unroll
    for (int n = 0; n < 8; n++) {
        float v = acc[0][n];
#pragma unroll
        for (int m = 1; m < KNN; m++) v = fmaxf(v, acc[m][n]);
        res[n] = fmaxf(v, 0.f);
    }
    const int node = node0 + ty;
    float4 r0, r1;
    r0.x = res[0]; r0.y = res[1]; r0.z = res[2]; r0.w = res[3];
    r1.x = res[4]; r1.y = res[5]; r1.z = res[6]; r1.w = res[7];
    *(float4*)(out + (size_t)node * HID + n0) = r0;
    *(float4*)(out + (size_t)node * HID + n0 + 4) = r1;
}

extern "C" void kernel_launch(void* const* d_in, const int* in_sizes, int n_in,
                              void* d_out, int out_size, void* d_ws, size_t ws_size,
                              hipStream_t stream) {
    const float* pos = (const float*)d_in[0];
    const int* ei = (const int*)d_in[1];
    const float* W1a = (const float*)d_in[2];
    const float* b1a = (const float*)d_in[3];
    const float* W1b = (const float*)d_in[4];
    const float* b1b = (const float*)d_in[5];
    const float* W2a = (const float*)d_in[6];
    const float* b2a = (const float*)d_in[7];
    const float* W2b = (const float*)d_in[8];
    const float* b2b = (const float*)d_in[9];
    const float* W3a = (const float*)d_in[10];
    const float* b3a = (const float*)d_in[11];
    const float* W3b = (const float*)d_in[12];
    const float* b3b = (const float*)d_in[13];

    float* h1 = (float*)d_ws;                       // [NODES][32]
    float* h2 = h1 + (size_t)NODES * 32;            // [NODES][64]
    float* outp = (float*)d_out;                    // [NODES][128]

    // Layer 1: CIN=6, HID=32; NB=32 nodes/block, 128 threads
    pnconv<3, 32, 32, 4><<<NODES / 32, 128, 0, stream>>>(
        pos, pos, ei, W1a, b1a, W1b, b1b, h1);
    // Layer 2: CIN=35, HID=64; NB=16 nodes/block, 128 threads
    pnconv<32, 64, 16, 8><<<NODES / 16, 128, 0, stream>>>(
        h1, pos, ei, W2a, b2a, W2b, b2b, h2);
    // Layer 3: CIN=67, HID=128; NB=8 nodes/block, 128 threads
    pnconv<64, 128, 8, 16><<<NODES / 8, 128, 0, stream>>>(
        h2, pos, ei, W3a, b3a, W3b, b3b, outp);
}

// Round 4
// 372.204 us; speedup vs baseline: 1.8521x; 1.5372x over previous
//
#include <hip/hip_runtime.h>

#define NODES 100000
#define KNN 6

typedef __attribute__((ext_vector_type(8))) short bf16x8;
typedef __attribute__((ext_vector_type(4))) float f32x4;

union U16 { uint4 u; bf16x8 b; };

__device__ __host__ inline unsigned short bf16_rn_u(unsigned u) {
    return (unsigned short)((u + 0x7FFF + ((u >> 16) & 1)) >> 16);
}
__device__ inline unsigned short bf16_rn(float x) {
    return bf16_rn_u(__float_as_uint(x));
}
__device__ inline float bf16_f(unsigned short h) {
    return __uint_as_float(((unsigned)h) << 16);
}
// pack: low16 = bf16(x), high16 = bf16(x - f32(low16))
__device__ inline unsigned pack_hilo(float x) {
    unsigned short hi = bf16_rn(x);
    float lo = x - bf16_f(hi);
    return (unsigned)hi | ((unsigned)bf16_rn(lo) << 16);
}

constexpr int cmax(int a, int b) { return a > b ? a : b; }

// ---------------------------------------------------------------------------
// Prep: convert weight matrix W[CIN_][N_] (fp32, row-major) into MFMA A-operand
// fragments, split into hi and lo bf16 arrays. Fragment (t, kt) holds
// A[m = t*16 + (lane&15)][k = kt*32 + (lane>>4)*8 + j], j=0..7 packed as uint4.
// Rows c >= CIN_ are zero (K padding).
template <int CIN_, int N_>
__global__ void prep_wfrag(const float* __restrict__ W,
                           uint4* __restrict__ fh, uint4* __restrict__ fl) {
    constexpr int KT = (CIN_ + 31) / 32;
    constexpr int NT = N_ / 16;
    int idx = blockIdx.x * blockDim.x + threadIdx.x;
    if (idx >= NT * KT * 64) return;
    int lane = idx & 63;
    int fk = idx >> 6;          // t*KT + kt
    int kt = fk % KT, t = fk / KT;
    int n = t * 16 + (lane & 15);
    int kbase = kt * 32 + (lane >> 4) * 8;
    unsigned h[4], l[4];
    for (int p = 0; p < 4; p++) {
        unsigned short hh[2], ll[2];
        for (int q = 0; q < 2; q++) {
            int c = kbase + 2 * p + q;
            float w = (c < CIN_) ? W[(size_t)c * N_ + n] : 0.f;
            unsigned short hi = bf16_rn(w);
            hh[q] = hi;
            ll[q] = bf16_rn(w - bf16_f(hi));
        }
        h[p] = (unsigned)hh[0] | ((unsigned)hh[1] << 16);
        l[p] = (unsigned)ll[0] | ((unsigned)ll[1] << 16);
    }
    fh[idx] = make_uint4(h[0], h[1], h[2], h[3]);
    fl[idx] = make_uint4(l[0], l[1], l[2], l[3]);
}

// ---------------------------------------------------------------------------
// MFMA PointNetConv layer (layers 2 and 3).
//   xp: packed hi|lo bf16 node features [NODES][CX] (u32 each)
//   out: fp32 [NODES][H] if !OUTP, packed u32 [NODES][H] if OUTP
// Both GEMMs computed transposed: D = W^T (A-op, regs) * data^T (B-op, LDS).
template <int CX, int H, bool OUTP>
__global__ __launch_bounds__(256, 2) void pnconv_mfma(
    const unsigned* __restrict__ xp,
    const float* __restrict__ pos,
    const int* __restrict__ ei,
    const uint4* __restrict__ wfa_hi, const uint4* __restrict__ wfa_lo,
    const float* __restrict__ ba,
    const uint4* __restrict__ wfb_hi, const uint4* __restrict__ wfb_lo,
    const float* __restrict__ bb,
    void* __restrict__ outv)
{
    constexpr int CIN = CX + 3;
    constexpr int K1T = (CIN + 31) / 32;   // K-tiles GEMM1
    constexpr int K2T = H / 32;            // K-tiles GEMM2
    constexpr int NT = H / 16;             // output-channel tiles
    constexpr int NW = NT / 4;             // tiles per wave
    constexpr int NB = 16, E = NB * KNN, MT1 = 6, MT2 = 8;  // 96 edges, 128 slots
    constexpr int K1P = K1T * 32 + 4;      // row stride (u32) of A1p
    constexpr int K2P = K2T * 32 + 4;      // row stride (u32) of Hp
    constexpr int UN = cmax(cmax(E * K1P, E * K2P), NB * H);

    __shared__ unsigned buf[UN];
    __shared__ int srcs[E];

    const int tid = threadIdx.x;
    const int lane = tid & 63;
    const int wv = tid >> 6;
    const int l15 = lane & 15;
    const int quad = lane >> 4;
    const int node0 = blockIdx.x * NB;
    const long e0 = (long)node0 * KNN;

    // ---- weight fragments (registers, loaded from prep output) ----
    bf16x8 wa_h[NW][K1T], wa_l[NW][K1T], wb_h[NW][K2T], wb_l[NW][K2T];
#pragma unroll
    for (int t = 0; t < NW; t++) {
        const int tg = wv * NW + t;
#pragma unroll
        for (int k = 0; k < K1T; k++) {
            U16 a, b;
            a.u = wfa_hi[(tg * K1T + k) * 64 + lane];
            b.u = wfa_lo[(tg * K1T + k) * 64 + lane];
            wa_h[t][k] = a.b; wa_l[t][k] = b.b;
        }
#pragma unroll
        for (int k = 0; k < K2T; k++) {
            U16 a, b;
            a.u = wfb_hi[(tg * K2T + k) * 64 + lane];
            b.u = wfb_lo[(tg * K2T + k) * 64 + lane];
            wb_h[t][k] = a.b; wb_l[t][k] = b.b;
        }
    }

    // ---- staging: A1p[e][k] = packed features ----
    if (tid < E) srcs[tid] = ei[e0 + tid];
    __syncthreads();

    constexpr int XC4 = CX / 4;
    for (int i = tid; i < E * XC4; i += 256) {
        const int e = i / XC4, c = i - e * XC4;
        const uint4 v = *(const uint4*)(xp + (size_t)srcs[e] * CX + 4 * c);
        *(uint4*)&buf[e * K1P + 4 * c] = v;
    }
    if (tid < E) {
        const int e = tid;
        const int s = srcs[e];
        const int nd = node0 + e / KNN;
        buf[e * K1P + CX + 0] = pack_hilo(pos[3 * s + 0] - pos[3 * nd + 0]);
        buf[e * K1P + CX + 1] = pack_hilo(pos[3 * s + 1] - pos[3 * nd + 1]);
        buf[e * K1P + CX + 2] = pack_hilo(pos[3 * s + 2] - pos[3 * nd + 2]);
        for (int k = CX + 3; k < K1T * 32; k++) buf[e * K1P + k] = 0;
    }
    __syncthreads();

    // ---- GEMM1: H^T[kh][edge] = sum_c W1t[kh][c] * A1^T[c][edge] ----
    f32x4 acc1[NW][MT1];
#pragma unroll
    for (int t = 0; t < NW; t++)
#pragma unroll
        for (int m = 0; m < MT1; m++) acc1[t][m] = (f32x4){0.f, 0.f, 0.f, 0.f};

#pragma unroll
    for (int kt = 0; kt < K1T; kt++) {
#pragma unroll
        for (int m = 0; m < MT1; m++) {
            const unsigned* p = &buf[(m * 16 + l15) * K1P + kt * 32 + quad * 8];
            const uint4 u0 = *(const uint4*)p;
            const uint4 u1 = *(const uint4*)(p + 4);
            U16 bh, bl;
            bh.u.x = __builtin_amdgcn_perm(u0.y, u0.x, 0x05040100u);
            bh.u.y = __builtin_amdgcn_perm(u0.w, u0.z, 0x05040100u);
            bh.u.z = __builtin_amdgcn_perm(u1.y, u1.x, 0x05040100u);
            bh.u.w = __builtin_amdgcn_perm(u1.w, u1.z, 0x05040100u);
            bl.u.x = __builtin_amdgcn_perm(u0.y, u0.x, 0x07060302u);
            bl.u.y = __builtin_amdgcn_perm(u0.w, u0.z, 0x07060302u);
            bl.u.z = __builtin_amdgcn_perm(u1.y, u1.x, 0x07060302u);
            bl.u.w = __builtin_amdgcn_perm(u1.w, u1.z, 0x07060302u);
#pragma unroll
            for (int t = 0; t < NW; t++) {
                acc1[t][m] = __builtin_amdgcn_mfma_f32_16x16x32_bf16(wa_h[t][kt], bh.b, acc1[t][m], 0, 0, 0);
                acc1[t][m] = __builtin_amdgcn_mfma_f32_16x16x32_bf16(wa_h[t][kt], bl.b, acc1[t][m], 0, 0, 0);
                acc1[t][m] = __builtin_amdgcn_mfma_f32_16x16x32_bf16(wa_l[t][kt], bh.b, acc1[t][m], 0, 0, 0);
            }
        }
    }
    __syncthreads();   // all A1p reads done; buf becomes Hp

    // ---- bias + relu + split + write Hp[e][kh] (b128: 4 consecutive kh) ----
#pragma unroll
    for (int t = 0; t < NW; t++) {
        const int khb = (wv * NW + t) * 16 + quad * 4;
        const float b0 = ba[khb], b1 = ba[khb + 1], b2 = ba[khb + 2], b3 = ba[khb + 3];
#pragma unroll
        for (int m = 0; m < MT1; m++) {
            const int e = m * 16 + l15;
            uint4 pk;
            pk.x = pack_hilo(fmaxf(acc1[t][m][0] + b0, 0.f));
            pk.y = pack_hilo(fmaxf(acc1[t][m][1] + b1, 0.f));
            pk.z = pack_hilo(fmaxf(acc1[t][m][2] + b2, 0.f));
            pk.w = pack_hilo(fmaxf(acc1[t][m][3] + b3, 0.f));
            *(uint4*)&buf[(size_t)e * K2P + khb] = pk;
        }
    }
    __syncthreads();

    // ---- GEMM2: O^T[n][slot], slots = 8 per node (6,7 duplicate 0) ----
    f32x4 acc2[NW][MT2];
#pragma unroll
    for (int t = 0; t < NW; t++)
#pragma unroll
        for (int m = 0; m < MT2; m++) acc2[t][m] = (f32x4){0.f, 0.f, 0.f, 0.f};

#pragma unroll
    for (int m = 0; m < MT2; m++) {
        const int slot = m * 16 + l15;
        const int ndl = slot >> 3;
        const int i7 = slot & 7;
        const int e = ndl * KNN + (i7 < KNN ? i7 : 0);
        const unsigned* rowp = &buf[(size_t)e * K2P];
#pragma unroll
        for (int kt = 0; kt < K2T; kt++) {
            const unsigned* p = rowp + kt * 32 + quad * 8;
            const uint4 u0 = *(const uint4*)p;
            const uint4 u1 = *(const uint4*)(p + 4);
            U16 bh, bl;
            bh.u.x = __builtin_amdgcn_perm(u0.y, u0.x, 0x05040100u);
            bh.u.y = __builtin_amdgcn_perm(u0.w, u0.z, 0x05040100u);
            bh.u.z = __builtin_amdgcn_perm(u1.y, u1.x, 0x05040100u);
            bh.u.w = __builtin_amdgcn_perm(u1.w, u1.z, 0x05040100u);
            bl.u.x = __builtin_amdgcn_perm(u0.y, u0.x, 0x07060302u);
            bl.u.y = __builtin_amdgcn_perm(u0.w, u0.z, 0x07060302u);
            bl.u.z = __builtin_amdgcn_perm(u1.y, u1.x, 0x07060302u);
            bl.u.w = __builtin_amdgcn_perm(u1.w, u1.z, 0x07060302u);
#pragma unroll
            for (int t = 0; t < NW; t++) {
                acc2[t][m] = __builtin_amdgcn_mfma_f32_16x16x32_bf16(wb_h[t][kt], bh.b, acc2[t][m], 0, 0, 0);
                acc2[t][m] = __builtin_amdgcn_mfma_f32_16x16x32_bf16(wb_h[t][kt], bl.b, acc2[t][m], 0, 0, 0);
                acc2[t][m] = __builtin_amdgcn_mfma_f32_16x16x32_bf16(wb_l[t][kt], bh.b, acc2[t][m], 0, 0, 0);
            }
        }
    }
    __syncthreads();   // all Hp reads done; buf becomes obuf

    // ---- segment max (shfl over 8-slot groups) + bias + relu → obuf ----
    const int c7 = l15 & 7;
#pragma unroll
    for (int t = 0; t < NW; t++) {
        const int nbase = (wv * NW + t) * 16 + quad * 4;
        const float bias_w = bb[nbase + (l15 & 3)];
#pragma unroll
        for (int m = 0; m < MT2; m++) {
            f32x4 a = acc2[t][m];
#pragma unroll
            for (int d = 1; d < 8; d <<= 1) {
                a[0] = fmaxf(a[0], __shfl_xor(a[0], d));
                a[1] = fmaxf(a[1], __shfl_xor(a[1], d));
                a[2] = fmaxf(a[2], __shfl_xor(a[2], d));
                a[3] = fmaxf(a[3], __shfl_xor(a[3], d));
            }
            if (c7 < 4) {
                float v = (c7 == 0) ? a[0] : (c7 == 1) ? a[1] : (c7 == 2) ? a[2] : a[3];
                v = fmaxf(v + bias_w, 0.f);
                const int node_l = (m * 16 + l15) >> 3;
                const int n = nbase + c7;
                buf[node_l * H + n] = OUTP ? pack_hilo(v) : __float_as_uint(v);
            }
        }
    }
    __syncthreads();

    // ---- coalesced copy obuf → global ----
    for (int i = tid; i < NB * H / 4; i += 256) {
        const uint4 v = *(const uint4*)&buf[4 * i];
        const int nd = (4 * i) / H, col = (4 * i) - nd * H;
        *(uint4*)((unsigned*)outv + (size_t)(node0 + nd) * H + col) = v;
    }
}

// ---------------------------------------------------------------------------
// Layer-1 VALU kernel (CIN=6 too small for MFMA). Emits packed hi|lo output.
template <int C_X, int HID, int NB, int TX, bool OUTP>
__global__ __launch_bounds__(NB * TX, 2) void pnconv(
    const float* __restrict__ x, const float* __restrict__ pos,
    const int* __restrict__ ei,
    const float* __restrict__ Wa, const float* __restrict__ ba,
    const float* __restrict__ Wb, const float* __restrict__ bb,
    void* __restrict__ outv)
{
    constexpr int CIN = C_X + 3;
    constexpr int M = NB * KNN;
    constexpr int MPAD = M + 1;
    constexpr int NT = TX * NB;

    __shared__ float At[CIN * MPAD];
    __shared__ float Ht[HID * MPAD];

    const int tid = threadIdx.x;
    const int node0 = blockIdx.x * NB;
    const long e0 = (long)node0 * KNN;

    for (int e = tid; e < M; e += NT) {
        const int s = ei[e0 + e];
        const int node = node0 + e / KNN;
        const float sx = pos[3 * s + 0], sy = pos[3 * s + 1], sz = pos[3 * s + 2];
        At[(C_X + 0) * MPAD + e] = sx - pos[3 * node + 0];
        At[(C_X + 1) * MPAD + e] = sy - pos[3 * node + 1];
        At[(C_X + 2) * MPAD + e] = sz - pos[3 * node + 2];
        if constexpr (C_X == 3) {
            At[0 * MPAD + e] = sx;
            At[1 * MPAD + e] = sy;
            At[2 * MPAD + e] = sz;
        }
    }
    __syncthreads();

    const int tx = tid % TX;
    const int ty = tid / TX;
    const int m0 = ty * KNN;
    const int n0 = tx * 8;

    float acc[KNN][8];

    auto run_gemm = [&](const float* __restrict__ W, const float* A, int K) {
        float4 wa0[4], wa1[4], wb0[4], wb1[4];
        float aa[4][KNN], ab[4][KNN];
        auto load = [&](int kb, float4* w0, float4* w1, float (*a)[KNN]) {
#pragma unroll
            for (int j = 0; j < 4; j++) {
                const float* wr = W + (size_t)(kb + j) * HID + n0;
                w0[j] = *(const float4*)wr;
                w1[j] = *(const float4*)(wr + 4);
#pragma unroll
                for (int m = 0; m < KNN; m++) a[j][m] = A[(kb + j) * MPAD + m0 + m];
            }
        };
        auto comp = [&](const float4* w0, const float4* w1, const float (*a)[KNN]) {
#pragma unroll
            for (int j = 0; j < 4; j++) {
                const float wv[8] = {w0[j].x, w0[j].y, w0[j].z, w0[j].w,
                                     w1[j].x, w1[j].y, w1[j].z, w1[j].w};
#pragma unroll
                for (int m = 0; m < KNN; m++)
#pragma unroll
                    for (int n = 0; n < 8; n++)
                        acc[m][n] = fmaf(a[j][m], wv[n], acc[m][n]);
            }
        };
        const int KM = K & ~7;
        if (KM >= 8) {
            load(0, wa0, wa1, aa);
            for (int kb = 0; kb < KM; kb += 8) {
                load(kb + 4, wb0, wb1, ab);
                comp(wa0, wa1, aa);
                const int kn = (kb + 8 < KM) ? kb + 8 : kb;
                load(kn, wa0, wa1, aa);
                comp(wb0, wb1, ab);
            }
        }
        for (int k = KM; k < K; k++) {
            const float* wr = W + (size_t)k * HID + n0;
            const float4 w0 = *(const float4*)wr;
            const float4 w1 = *(const float4*)(wr + 4);
            const float wv[8] = {w0.x, w0.y, w0.z, w0.w, w1.x, w1.y, w1.z, w1.w};
            float a[KNN];
#pragma unroll
            for (int m = 0; m < KNN; m++) a[m] = A[k * MPAD + m0 + m];
#pragma unroll
            for (int m = 0; m < KNN; m++)
#pragma unroll
                for (int n = 0; n < 8; n++)
                    acc[m][n] = fmaf(a[m], wv[n], acc[m][n]);
        }
    };

    {
        const float4 q0 = *(const float4*)(ba + n0);
        const float4 q1 = *(const float4*)(ba + n0 + 4);
#pragma unroll
        for (int m = 0; m < KNN; m++) {
            acc[m][0] = q0.x; acc[m][1] = q0.y; acc[m][2] = q0.z; acc[m][3] = q0.w;
            acc[m][4] = q1.x; acc[m][5] = q1.y; acc[m][6] = q1.z; acc[m][7] = q1.w;
        }
    }
    run_gemm(Wa, At, CIN);
#pragma unroll
    for (int n = 0; n < 8; n++)
#pragma unroll
        for (int m = 0; m < KNN; m++)
            Ht[(n0 + n) * MPAD + m0 + m] = fmaxf(acc[m][n], 0.f);
    __syncthreads();

    {
        const float4 q0 = *(const float4*)(bb + n0);
        const float4 q1 = *(const float4*)(bb + n0 + 4);
#pragma unroll
        for (int m = 0; m < KNN; m++) {
            acc[m][0] = q0.x; acc[m][1] = q0.y; acc[m][2] = q0.z; acc[m][3] = q0.w;
            acc[m][4] = q1.x; acc[m][5] = q1.y; acc[m][6] = q1.z; acc[m][7] = q1.w;
        }
    }
    run_gemm(Wb, Ht, HID);

    float res[8];
#pragma unroll
    for (int n = 0; n < 8; n++) {
        float v = acc[0][n];
#pragma unroll
        for (int m = 1; m < KNN; m++) v = fmaxf(v, acc[m][n]);
        res[n] = fmaxf(v, 0.f);
    }
    const int node = node0 + ty;
    if constexpr (OUTP) {
        unsigned* op = (unsigned*)outv;
        uint4 p0, p1;
        p0.x = pack_hilo(res[0]); p0.y = pack_hilo(res[1]);
        p0.z = pack_hilo(res[2]); p0.w = pack_hilo(res[3]);
        p1.x = pack_hilo(res[4]); p1.y = pack_hilo(res[5]);
        p1.z = pack_hilo(res[6]); p1.w = pack_hilo(res[7]);
        *(uint4*)(op + (size_t)node * HID + n0) = p0;
        *(uint4*)(op + (size_t)node * HID + n0 + 4) = p1;
    } else {
        float* op = (float*)outv;
        float4 r0, r1;
        r0.x = res[0]; r0.y = res[1]; r0.z = res[2]; r0.w = res[3];
        r1.x = res[4]; r1.y = res[5]; r1.z = res[6]; r1.w = res[7];
        *(float4*)(op + (size_t)node * HID + n0) = r0;
        *(float4*)(op + (size_t)node * HID + n0 + 4) = r1;
    }
}

// ---------------------------------------------------------------------------
extern "C" void kernel_launch(void* const* d_in, const int* in_sizes, int n_in,
                              void* d_out, int out_size, void* d_ws, size_t ws_size,
                              hipStream_t stream) {
    const float* pos = (const float*)d_in[0];
    const int* ei = (const int*)d_in[1];
    const float* W1a = (const float*)d_in[2];
    const float* b1a = (const float*)d_in[3];
    const float* W1b = (const float*)d_in[4];
    const float* b1b = (const float*)d_in[5];
    const float* W2a = (const float*)d_in[6];
    const float* b2a = (const float*)d_in[7];
    const float* W2b = (const float*)d_in[8];
    const float* b2b = (const float*)d_in[9];
    const float* W3a = (const float*)d_in[10];
    const float* b3a = (const float*)d_in[11];
    const float* W3b = (const float*)d_in[12];
    const float* b3b = (const float*)d_in[13];

    unsigned* ws = (unsigned*)d_ws;
    unsigned* h1p = ws;                                   // [NODES][32] u32
    unsigned* h2p = ws + (size_t)NODES * 32;              // [NODES][64] u32
    uint4* wf = (uint4*)(ws + (size_t)NODES * 96);        // weight fragments
    // fragment-array uint4 counts: W2a(NT=4,KT=2)=512, W2b(4,2)=512,
    //                              W3a(8,3)=1536,     W3b(8,4)=2048
    uint4* wf2a_h = wf;             uint4* wf2a_l = wf + 512;
    uint4* wf2b_h = wf + 1024;      uint4* wf2b_l = wf + 1536;
    uint4* wf3a_h = wf + 2048;      uint4* wf3a_l = wf + 3584;
    uint4* wf3b_h = wf + 5120;      uint4* wf3b_l = wf + 7168;   // end 9216

    prep_wfrag<35, 64><<<2, 256, 0, stream>>>(W2a, wf2a_h, wf2a_l);
    prep_wfrag<64, 64><<<2, 256, 0, stream>>>(W2b, wf2b_h, wf2b_l);
    prep_wfrag<67, 128><<<6, 256, 0, stream>>>(W3a, wf3a_h, wf3a_l);
    prep_wfrag<128, 128><<<8, 256, 0, stream>>>(W3b, wf3b_h, wf3b_l);

    // Layer 1 (VALU, packed output)
    pnconv<3, 32, 32, 4, true><<<NODES / 32, 128, 0, stream>>>(
        pos, pos, ei, W1a, b1a, W1b, b1b, h1p);
    // Layer 2 (MFMA bf16x3): h1p -> h2p
    pnconv_mfma<32, 64, true><<<NODES / 16, 256, 0, stream>>>(
        h1p, pos, ei, wf2a_h, wf2a_l, b2a, wf2b_h, wf2b_l, b2b, h2p);
    // Layer 3 (MFMA bf16x3): h2p -> out (fp32)
    pnconv_mfma<64, 128, false><<<NODES / 16, 256, 0, stream>>>(
        h2p, pos, ei, wf3a_h, wf3a_l, b3a, wf3b_h, wf3b_l, b3b, d_out);
}

// Round 5
// 280.811 us; speedup vs baseline: 2.4549x; 1.3255x over previous
//
#include <hip/hip_runtime.h>

#define NODES 100000
#define KNN 6

typedef unsigned short u16t;
typedef __attribute__((ext_vector_type(8))) short bf16x8;
typedef __attribute__((ext_vector_type(4))) float f32x4;
union U16 { uint4 u; bf16x8 b; };

__device__ inline f32x4 mfma16(bf16x8 a, bf16x8 b, f32x4 c) {
    return __builtin_amdgcn_mfma_f32_16x16x32_bf16(a, b, c, 0, 0, 0);
}
// pack top-16 bits of two fp32 words (u0 -> low half, u1 -> high half)
__device__ inline unsigned top2(unsigned u1, unsigned u0) {
    return __builtin_amdgcn_perm(u1, u0, 0x07060302u);
}
__device__ inline u16t bf16_rn(float x) {
    unsigned u = __float_as_uint(x);
    return (u16t)((u + 0x7FFF + ((u >> 16) & 1)) >> 16);
}
__device__ inline float bf16_f(u16t h) {
    return __uint_as_float(((unsigned)h) << 16);
}

// ---------------------------------------------------------------------------
// Weight prep: W[CIN_][N_] fp32 -> MFMA fragments (hi / lo bf16 planes).
// Fragment (tile t, k-tile kt): elem[n = t*16 + (lane&15)][k = kt*32 + (lane>>4)*8 + j]
// packed as uint4 (8 bf16). Rows c >= CIN_ are zero.
template <int CIN_, int N_>
__device__ void prep_dev(const float* __restrict__ W,
                         uint4* __restrict__ fh, uint4* __restrict__ fl, int idx) {
    constexpr int KT = (CIN_ + 31) / 32;
    constexpr int NTt = N_ / 16;
    if (idx >= NTt * KT * 64) return;
    const int lane = idx & 63;
    const int fk = idx >> 6;
    const int kt = fk % KT, t = fk / KT;
    const int n = t * 16 + (lane & 15);
    const int kbase = kt * 32 + (lane >> 4) * 8;
    unsigned h[4], l[4];
    for (int p = 0; p < 4; p++) {
        u16t hh[2], ll[2];
        for (int q = 0; q < 2; q++) {
            const int c = kbase + 2 * p + q;
            const float w = (c < CIN_) ? W[(size_t)c * N_ + n] : 0.f;
            const u16t hi = bf16_rn(w);
            hh[q] = hi;
            ll[q] = bf16_rn(w - bf16_f(hi));
        }
        h[p] = (unsigned)hh[0] | ((unsigned)hh[1] << 16);
        l[p] = (unsigned)ll[0] | ((unsigned)ll[1] << 16);
    }
    fh[idx] = make_uint4(h[0], h[1], h[2], h[3]);
    fl[idx] = make_uint4(l[0], l[1], l[2], l[3]);
}

__global__ void prep_all(const float* W2a, const float* W2b,
                         const float* W3a, const float* W3b, uint4* wf) {
    const int b = blockIdx.x, t = threadIdx.x;
    if (b < 2)       prep_dev<35, 64>(W2a, wf + 0,    wf + 512,  b * 256 + t);
    else if (b < 4)  prep_dev<64, 64>(W2b, wf + 1024, wf + 1536, (b - 2) * 256 + t);
    else if (b < 10) prep_dev<67, 128>(W3a, wf + 2048, wf + 3584, (b - 4) * 256 + t);
    else             prep_dev<128, 128>(W3b, wf + 5120, wf + 7168, (b - 10) * 256 + t);
}

// ---------------------------------------------------------------------------
// MFMA PointNetConv layer (layers 2, 3). Features stored as separate hi/lo
// bf16 planes (no packing/unpacking in the K-loops).
// GEMM1: A = weights (regs, preloaded), B = data (LDS)   -> rows=channels, cols=edges
// GEMM2: A = data (LDS), B = weights (regs, kt-streamed) -> rows=slots,    cols=channels
template <int CX, int H, int NWAVE, bool OUTP>
__global__ __launch_bounds__(NWAVE * 64, 4) void pnconv_mfma(
    const u16t* __restrict__ xh, const u16t* __restrict__ xl,
    const float* __restrict__ pos, const int* __restrict__ ei,
    const uint4* __restrict__ wfa_hi, const uint4* __restrict__ wfa_lo,
    const float* __restrict__ ba,
    const uint4* __restrict__ wfb_hi, const uint4* __restrict__ wfb_lo,
    const float* __restrict__ bb,
    float* __restrict__ outf, u16t* __restrict__ oh, u16t* __restrict__ ol)
{
    constexpr int NTH = NWAVE * 64;
    constexpr int CIN = CX + 3;
    constexpr int K1T = (CIN + 31) / 32;
    constexpr int K2T = H / 32;
    constexpr int NW = (H / 16) / NWAVE;     // channel tiles per wave
    constexpr int NB = 16, E = NB * KNN;     // 96 edges / block
    constexpr int MT1 = E / 16;              // 6 edge tiles
    constexpr int MT2 = NB * 8 / 16;         // 8 slot tiles (8 slots/node, 6,7 dup 0)
    constexpr int K1P = K1T * 32 + 8;        // ushort row stride, bank-conflict-free
    constexpr int K2P = K2T * 32 + 8;
    constexpr int APL = E * K1P;             // ushorts per A plane
    constexpr int HPL = E * K2P;             // ushorts per H plane
    constexpr int SM = (2 * APL > 2 * HPL) ? 2 * APL : 2 * HPL;

    __shared__ u16t smem[SM];
    __shared__ int srcs[E];

    const int tid = threadIdx.x;
    const int lane = tid & 63, wv = tid >> 6;
    const int l15 = lane & 15, quad = lane >> 4;
    const int node0 = blockIdx.x * NB;
    const long e0 = (long)node0 * KNN;

    if (tid < E) srcs[tid] = ei[e0 + tid];

    // GEMM1 weight fragments: load now, latency hidden behind staging
    U16 wah[NW][K1T], wal[NW][K1T];
#pragma unroll
    for (int t = 0; t < NW; t++)
#pragma unroll
        for (int kt = 0; kt < K1T; kt++) {
            const int fi = ((wv * NW + t) * K1T + kt) * 64 + lane;
            wah[t][kt].u = wfa_hi[fi];
            wal[t][kt].u = wfa_lo[fi];
        }

    __syncthreads();

    // ---- stage feature planes into LDS (plane copies, no unpack)
    constexpr int C8 = CX / 8;
    for (int i = tid; i < E * C8; i += NTH) {
        const int e = i / C8, c = i % C8;
        const size_t sb = (size_t)srcs[e] * CX + c * 8;
        *(uint4*)&smem[e * K1P + c * 8] = *(const uint4*)&xh[sb];
        *(uint4*)&smem[APL + e * K1P + c * 8] = *(const uint4*)&xl[sb];
    }
    if (tid < E) {
        const int e = tid, s = srcs[e], nd = node0 + e / KNN;
#pragma unroll
        for (int d = 0; d < 3; d++) {
            const float v = pos[3 * s + d] - pos[3 * nd + d];
            const unsigned u = __float_as_uint(v);
            smem[e * K1P + CX + d] = (u16t)(u >> 16);
            const float hif = __uint_as_float(u & 0xFFFF0000u);
            smem[APL + e * K1P + CX + d] = (u16t)(__float_as_uint(v - hif) >> 16);
        }
    }
    // zero the K padding (weight pad is zero too, but LDS junk could be Inf/NaN)
    constexpr int PADA = (CIN + 7) & ~7;
    constexpr int NU4 = (K1P - PADA) / 8;
    for (int i = tid; i < 2 * E; i += NTH) {
        const int pl = (i >= E) ? 1 : 0;
        const int e = i - pl * E;
        u16t* row = &smem[pl * APL + e * K1P];
        for (int k = CIN; k < PADA; k++) row[k] = 0;
        for (int j = 0; j < NU4; j++) *(uint4*)&row[PADA + j * 8] = make_uint4(0, 0, 0, 0);
    }
    __syncthreads();

    // ---- GEMM1: D[channel][edge] = W1^T * A^T  (3-term bf16 split)
    f32x4 acc1[NW][MT1];
#pragma unroll
    for (int t = 0; t < NW; t++)
#pragma unroll
        for (int m = 0; m < MT1; m++) acc1[t][m] = (f32x4){0.f, 0.f, 0.f, 0.f};

#pragma unroll
    for (int kt = 0; kt < K1T; kt++) {
#pragma unroll
        for (int m = 0; m < MT1; m++) {
            const u16t* p = &smem[(m * 16 + l15) * K1P + kt * 32 + quad * 8];
            U16 dh, dl;
            dh.u = *(const uint4*)p;
            dl.u = *(const uint4*)(p + APL);
#pragma unroll
            for (int t = 0; t < NW; t++) {
                acc1[t][m] = mfma16(wah[t][kt].b, dh.b, acc1[t][m]);
                acc1[t][m] = mfma16(wah[t][kt].b, dl.b, acc1[t][m]);
                acc1[t][m] = mfma16(wal[t][kt].b, dh.b, acc1[t][m]);
            }
        }
    }

    // GEMM2 weight ping-pong: preload kt=0 (latency covered by epilogue+barrier)
    U16 wbh[2][NW], wbl[2][NW];
#pragma unroll
    for (int t = 0; t < NW; t++) {
        const int fi = ((wv * NW + t) * K2T) * 64 + lane;
        wbh[0][t].u = wfb_hi[fi];
        wbl[0][t].u = wfb_lo[fi];
    }

    __syncthreads();   // all A reads done; smem becomes Hp planes

    // ---- bias + relu + trunc-split, write Hp planes (b64 per plane)
#pragma unroll
    for (int t = 0; t < NW; t++) {
        const int khb = (wv * NW + t) * 16 + quad * 4;
        const float4 bs = *(const float4*)&ba[khb];
#pragma unroll
        for (int m = 0; m < MT1; m++) {
            const float v0 = fmaxf(acc1[t][m][0] + bs.x, 0.f);
            const float v1 = fmaxf(acc1[t][m][1] + bs.y, 0.f);
            const float v2 = fmaxf(acc1[t][m][2] + bs.z, 0.f);
            const float v3 = fmaxf(acc1[t][m][3] + bs.w, 0.f);
            const unsigned u0 = __float_as_uint(v0), u1 = __float_as_uint(v1);
            const unsigned u2 = __float_as_uint(v2), u3 = __float_as_uint(v3);
            uint2 hw, lw;
            hw.x = top2(u1, u0);
            hw.y = top2(u3, u2);
            const float l0 = v0 - __uint_as_float(u0 & 0xFFFF0000u);
            const float l1 = v1 - __uint_as_float(u1 & 0xFFFF0000u);
            const float l2 = v2 - __uint_as_float(u2 & 0xFFFF0000u);
            const float l3 = v3 - __uint_as_float(u3 & 0xFFFF0000u);
            lw.x = top2(__float_as_uint(l1), __float_as_uint(l0));
            lw.y = top2(__float_as_uint(l3), __float_as_uint(l2));
            u16t* wp = &smem[(m * 16 + l15) * K2P + khb];
            *(uint2*)wp = hw;
            *(uint2*)(wp + HPL) = lw;
        }
    }
    __syncthreads();

    // ---- GEMM2 (swapped): D[slot][channel] = Hp * W2, weights streamed per kt
    int eaddr[MT2];
#pragma unroll
    for (int m = 0; m < MT2; m++) {
        const int slot = m * 16 + l15;
        const int i7 = slot & 7;
        const int e2 = (slot >> 3) * KNN + (i7 < KNN ? i7 : 0);
        eaddr[m] = e2 * K2P + quad * 8;
    }

    f32x4 acc2[NW][MT2];
#pragma unroll
    for (int t = 0; t < NW; t++)
#pragma unroll
        for (int m = 0; m < MT2; m++) acc2[t][m] = (f32x4){0.f, 0.f, 0.f, 0.f};

#pragma unroll
    for (int kt = 0; kt < K2T; kt++) {
        const int cur = kt & 1, nxt = cur ^ 1;
        const int nkt = (kt + 1 < K2T) ? kt + 1 : kt;
#pragma unroll
        for (int t = 0; t < NW; t++) {      // prefetch next kt's weights
            const int fi = ((wv * NW + t) * K2T + nkt) * 64 + lane;
            wbh[nxt][t].u = wfb_hi[fi];
            wbl[nxt][t].u = wfb_lo[fi];
        }
#pragma unroll
        for (int m = 0; m < MT2; m++) {
            const u16t* p = &smem[eaddr[m] + kt * 32];
            U16 dh, dl;
            dh.u = *(const uint4*)p;
            dl.u = *(const uint4*)(p + HPL);
#pragma unroll
            for (int t = 0; t < NW; t++) {
                acc2[t][m] = mfma16(dh.b, wbh[cur][t].b, acc2[t][m]);
                acc2[t][m] = mfma16(dh.b, wbl[cur][t].b, acc2[t][m]);
                acc2[t][m] = mfma16(dl.b, wbh[cur][t].b, acc2[t][m]);
            }
        }
    }

    // ---- segment max: 3 in-lane fmax + 1 cross-quad shfl; direct global store
#pragma unroll
    for (int t = 0; t < NW; t++) {
        const int nb = (wv * NW + t) * 16;
        const float bias = bb[nb + l15];
#pragma unroll
        for (int m = 0; m < MT2; m++) {
            const f32x4 a = acc2[t][m];
            float v = fmaxf(fmaxf(a[0], a[1]), fmaxf(a[2], a[3]));
            v = fmaxf(v, __shfl_xor(v, 16));
            v = fmaxf(v + bias, 0.f);
            if ((quad & 1) == 0) {
                const int node = node0 + 2 * m + (quad >> 1);
                const size_t oidx = (size_t)node * H + nb + l15;
                if constexpr (OUTP) {
                    const unsigned u = __float_as_uint(v);
                    oh[oidx] = (u16t)(u >> 16);
                    const float hif = __uint_as_float(u & 0xFFFF0000u);
                    ol[oidx] = (u16t)(__float_as_uint(v - hif) >> 16);
                } else {
                    outf[oidx] = v;
                }
            }
        }
    }
}

// ---------------------------------------------------------------------------
// Layer-1 VALU kernel (CIN=6 too small for MFMA); outputs hi/lo bf16 planes.
__global__ __launch_bounds__(128, 2) void pnconv1(
    const float* __restrict__ pos, const int* __restrict__ ei,
    const float* __restrict__ Wa, const float* __restrict__ ba,
    const float* __restrict__ Wb, const float* __restrict__ bb,
    u16t* __restrict__ oh, u16t* __restrict__ ol)
{
    constexpr int C_X = 3, HID = 32, NB = 32, TX = 4;
    constexpr int CIN = C_X + 3;
    constexpr int M = NB * KNN;
    constexpr int MPAD = M + 1;
    constexpr int NTH = TX * NB;

    __shared__ float At[CIN * MPAD];
    __shared__ float Ht[HID * MPAD];

    const int tid = threadIdx.x;
    const int node0 = blockIdx.x * NB;
    const long e0 = (long)node0 * KNN;

    for (int e = tid; e < M; e += NTH) {
        const int s = ei[e0 + e];
        const int node = node0 + e / KNN;
        const float sx = pos[3 * s + 0], sy = pos[3 * s + 1], sz = pos[3 * s + 2];
        At[0 * MPAD + e] = sx;
        At[1 * MPAD + e] = sy;
        At[2 * MPAD + e] = sz;
        At[3 * MPAD + e] = sx - pos[3 * node + 0];
        At[4 * MPAD + e] = sy - pos[3 * node + 1];
        At[5 * MPAD + e] = sz - pos[3 * node + 2];
    }
    __syncthreads();

    const int tx = tid % TX;
    const int ty = tid / TX;
    const int m0 = ty * KNN;
    const int n0 = tx * 8;

    float acc[KNN][8];

    auto run_gemm = [&](const float* __restrict__ W, const float* A, int K) {
        float4 wa0[4], wa1[4], wb0[4], wb1[4];
        float aa[4][KNN], ab[4][KNN];
        auto load = [&](int kb, float4* w0, float4* w1, float (*a)[KNN]) {
#pragma unroll
            for (int j = 0; j < 4; j++) {
                const float* wr = W + (size_t)(kb + j) * HID + n0;
                w0[j] = *(const float4*)wr;
                w1[j] = *(const float4*)(wr + 4);
#pragma unroll
                for (int m = 0; m < KNN; m++) a[j][m] = A[(kb + j) * MPAD + m0 + m];
            }
        };
        auto comp = [&](const float4* w0, const float4* w1, const float (*a)[KNN]) {
#pragma unroll
            for (int j = 0; j < 4; j++) {
                const float wvv[8] = {w0[j].x, w0[j].y, w0[j].z, w0[j].w,
                                      w1[j].x, w1[j].y, w1[j].z, w1[j].w};
#pragma unroll
                for (int m = 0; m < KNN; m++)
#pragma unroll
                    for (int n = 0; n < 8; n++)
                        acc[m][n] = fmaf(a[j][m], wvv[n], acc[m][n]);
            }
        };
        const int KM = K & ~7;
        if (KM >= 8) {
            load(0, wa0, wa1, aa);
            for (int kb = 0; kb < KM; kb += 8) {
                load(kb + 4, wb0, wb1, ab);
                comp(wa0, wa1, aa);
                const int kn = (kb + 8 < KM) ? kb + 8 : kb;
                load(kn, wa0, wa1, aa);
                comp(wb0, wb1, ab);
            }
        }
        for (int k = KM; k < K; k++) {
            const float* wr = W + (size_t)k * HID + n0;
            const float4 w0 = *(const float4*)wr;
            const float4 w1 = *(const float4*)(wr + 4);
            const float wvv[8] = {w0.x, w0.y, w0.z, w0.w, w1.x, w1.y, w1.z, w1.w};
            float a[KNN];
#pragma unroll
            for (int m = 0; m < KNN; m++) a[m] = A[k * MPAD + m0 + m];
#pragma unroll
            for (int m = 0; m < KNN; m++)
#pragma unroll
                for (int n = 0; n < 8; n++)
                    acc[m][n] = fmaf(a[m], wvv[n], acc[m][n]);
        }
    };

    {
        const float4 q0 = *(const float4*)(ba + n0);
        const float4 q1 = *(const float4*)(ba + n0 + 4);
#pragma unroll
        for (int m = 0; m < KNN; m++) {
            acc[m][0] = q0.x; acc[m][1] = q0.y; acc[m][2] = q0.z; acc[m][3] = q0.w;
            acc[m][4] = q1.x; acc[m][5] = q1.y; acc[m][6] = q1.z; acc[m][7] = q1.w;
        }
    }
    run_gemm(Wa, At, CIN);
#pragma unroll
    for (int n = 0; n < 8; n++)
#pragma unroll
        for (int m = 0; m < KNN; m++)
            Ht[(n0 + n) * MPAD + m0 + m] = fmaxf(acc[m][n], 0.f);
    __syncthreads();

    {
        const float4 q0 = *(const float4*)(bb + n0);
        const float4 q1 = *(const float4*)(bb + n0 + 4);
#pragma unroll
        for (int m = 0; m < KNN; m++) {
            acc[m][0] = q0.x; acc[m][1] = q0.y; acc[m][2] = q0.z; acc[m][3] = q0.w;
            acc[m][4] = q1.x; acc[m][5] = q1.y; acc[m][6] = q1.z; acc[m][7] = q1.w;
        }
    }
    run_gemm(Wb, Ht, HID);

    float res[8];
#pragma unroll
    for (int n = 0; n < 8; n++) {
        float v = acc[0][n];
#pragma unroll
        for (int m = 1; m < KNN; m++) v = fmaxf(v, acc[m][n]);
        res[n] = fmaxf(v, 0.f);
    }
    const int node = node0 + ty;
    unsigned hu[8];
    float lov[8];
#pragma unroll
    for (int i = 0; i < 8; i++) {
        const unsigned u = __float_as_uint(res[i]);
        hu[i] = u;
        lov[i] = res[i] - __uint_as_float(u & 0xFFFF0000u);
    }
    uint4 hv, lv;
    hv.x = top2(hu[1], hu[0]); hv.y = top2(hu[3], hu[2]);
    hv.z = top2(hu[5], hu[4]); hv.w = top2(hu[7], hu[6]);
    lv.x = top2(__float_as_uint(lov[1]), __float_as_uint(lov[0]));
    lv.y = top2(__float_as_uint(lov[3]), __float_as_uint(lov[2]));
    lv.z = top2(__float_as_uint(lov[5]), __float_as_uint(lov[4]));
    lv.w = top2(__float_as_uint(lov[7]), __float_as_uint(lov[6]));
    *(uint4*)&oh[(size_t)node * HID + n0] = hv;
    *(uint4*)&ol[(size_t)node * HID + n0] = lv;
}

// ---------------------------------------------------------------------------
extern "C" void kernel_launch(void* const* d_in, const int* in_sizes, int n_in,
                              void* d_out, int out_size, void* d_ws, size_t ws_size,
                              hipStream_t stream) {
    const float* pos = (const float*)d_in[0];
    const int* ei = (const int*)d_in[1];
    const float* W1a = (const float*)d_in[2];
    const float* b1a = (const float*)d_in[3];
    const float* W1b = (const float*)d_in[4];
    const float* b1b = (const float*)d_in[5];
    const float* W2a = (const float*)d_in[6];
    const float* b2a = (const float*)d_in[7];
    const float* W2b = (const float*)d_in[8];
    const float* b2b = (const float*)d_in[9];
    const float* W3a = (const float*)d_in[10];
    const float* b3a = (const float*)d_in[11];
    const float* W3b = (const float*)d_in[12];
    const float* b3b = (const float*)d_in[13];

    u16t* h1h = (u16t*)d_ws;                       // [NODES][32] hi plane
    u16t* h1l = h1h + (size_t)NODES * 32;          // [NODES][32] lo plane
    u16t* h2h = h1l + (size_t)NODES * 32;          // [NODES][64] hi plane
    u16t* h2l = h2h + (size_t)NODES * 64;          // [NODES][64] lo plane
    uint4* wf = (uint4*)(h2l + (size_t)NODES * 64);
    // fragment uint4 offsets: W2a h/l @0/512, W2b @1024/1536,
    //                         W3a @2048/3584 (len1536), W3b @5120/7168 (len2048)

    prep_all<<<18, 256, 0, stream>>>(W2a, W2b, W3a, W3b, wf);

    pnconv1<<<NODES / 32, 128, 0, stream>>>(pos, ei, W1a, b1a, W1b, b1b, h1h, h1l);

    // Layer 2: CX=32, H=64, 2 waves (NW=2 channel tiles/wave)
    pnconv_mfma<32, 64, 2, true><<<NODES / 16, 128, 0, stream>>>(
        h1h, h1l, pos, ei,
        wf + 0, wf + 512, b2a, wf + 1024, wf + 1536, b2b,
        nullptr, h2h, h2l);

    // Layer 3: CX=64, H=128, 4 waves (NW=2), fp32 output
    pnconv_mfma<64, 128, 4, false><<<NODES / 16, 256, 0, stream>>>(
        h2h, h2l, pos, ei,
        wf + 2048, wf + 3584, b3a, wf + 5120, wf + 7168, b3b,
        (float*)d_out, nullptr, nullptr);
}

// Round 6
// 253.430 us; speedup vs baseline: 2.7202x; 1.1080x over previous
//
#include <hip/hip_runtime.h>

#define NODES 100000
#define KNN 6

typedef unsigned short u16t;
typedef __attribute__((ext_vector_type(8))) short bf16x8;
typedef __attribute__((ext_vector_type(4))) float f32x4;
union U16 { uint4 u; bf16x8 b; };

__device__ inline f32x4 mfma16(bf16x8 a, bf16x8 b, f32x4 c) {
    return __builtin_amdgcn_mfma_f32_16x16x32_bf16(a, b, c, 0, 0, 0);
}
// pack top-16 bits of two fp32 words (u0 -> low half, u1 -> high half)
__device__ inline unsigned top2(unsigned u1, unsigned u0) {
    return __builtin_amdgcn_perm(u1, u0, 0x07060302u);
}
__device__ inline u16t bf16_rn(float x) {
    unsigned u = __float_as_uint(x);
    return (u16t)((u + 0x7FFF + ((u >> 16) & 1)) >> 16);
}
__device__ inline float bf16_f(u16t h) {
    return __uint_as_float(((unsigned)h) << 16);
}
// truncation split into hi/lo bf16 planes
__device__ inline void split_store(u16t* hp, u16t* lp, float v) {
    const unsigned u = __float_as_uint(v);
    *hp = (u16t)(u >> 16);
    const float hif = __uint_as_float(u & 0xFFFF0000u);
    *lp = (u16t)(__float_as_uint(v - hif) >> 16);
}

// ---------------------------------------------------------------------------
// Weight prep: W[CIN_][N_] fp32 -> MFMA A-operand fragments (hi/lo bf16).
// Fragment (tile t, k-tile kt): elem[n = t*16 + (lane&15)][k = kt*32 + (lane>>4)*8 + j]
template <int CIN_, int N_>
__device__ void prep_dev(const float* __restrict__ W,
                         uint4* __restrict__ fh, uint4* __restrict__ fl, int idx) {
    constexpr int KT = (CIN_ + 31) / 32;
    constexpr int NTt = N_ / 16;
    if (idx >= NTt * KT * 64) return;
    const int lane = idx & 63;
    const int fk = idx >> 6;
    const int kt = fk % KT, t = fk / KT;
    const int n = t * 16 + (lane & 15);
    const int kbase = kt * 32 + (lane >> 4) * 8;
    unsigned h[4], l[4];
    for (int p = 0; p < 4; p++) {
        u16t hh[2], ll[2];
        for (int q = 0; q < 2; q++) {
            const int c = kbase + 2 * p + q;
            const float w = (c < CIN_) ? W[(size_t)c * N_ + n] : 0.f;
            const u16t hi = bf16_rn(w);
            hh[q] = hi;
            ll[q] = bf16_rn(w - bf16_f(hi));
        }
        h[p] = (unsigned)hh[0] | ((unsigned)hh[1] << 16);
        l[p] = (unsigned)ll[0] | ((unsigned)ll[1] << 16);
    }
    fh[idx] = make_uint4(h[0], h[1], h[2], h[3]);
    fl[idx] = make_uint4(l[0], l[1], l[2], l[3]);
}

__global__ void prep_all(const float* W1a, const float* W1b,
                         const float* W2a, const float* W2b,
                         const float* W3a, const float* W3b, uint4* wf) {
    const int b = blockIdx.x, t = threadIdx.x;
    if (b == 0)      prep_dev<6, 32>(W1a, wf + 0, wf + 128, t);
    else if (b == 1) prep_dev<32, 32>(W1b, wf + 256, wf + 384, t);
    else if (b < 4)  prep_dev<35, 64>(W2a, wf + 512, wf + 1024, (b - 2) * 256 + t);
    else if (b < 6)  prep_dev<64, 64>(W2b, wf + 1536, wf + 2048, (b - 4) * 256 + t);
    else if (b < 12) prep_dev<67, 128>(W3a, wf + 2560, wf + 4096, (b - 6) * 256 + t);
    else             prep_dev<128, 128>(W3b, wf + 5632, wf + 7680, (b - 12) * 256 + t);
}

// ---------------------------------------------------------------------------
// MFMA PointNetConv layer (all 3 layers). Features as separate hi/lo bf16 planes.
// CX==3: layer-1 mode (features = pos, staged directly; no x-gather).
// GEMM1: A = weights (regs, kt-streamed), B = data (LDS)   rows=channels, cols=edges
// GEMM2: A = data (LDS), B = weights (regs, kt-streamed)   rows=slots,    cols=channels
template <int CX, int H, int NWAVE, int NB, bool OUTP>
__global__ __launch_bounds__(NWAVE * 64, 4) void pnconv_mfma(
    const u16t* __restrict__ xh, const u16t* __restrict__ xl,
    const float* __restrict__ pos, const int* __restrict__ ei,
    const uint4* __restrict__ wfa_hi, const uint4* __restrict__ wfa_lo,
    const float* __restrict__ ba,
    const uint4* __restrict__ wfb_hi, const uint4* __restrict__ wfb_lo,
    const float* __restrict__ bb,
    float* __restrict__ outf, u16t* __restrict__ oh, u16t* __restrict__ ol)
{
    constexpr int NTH = NWAVE * 64;
    constexpr int CIN = CX + 3;
    constexpr int K1T = (CIN + 31) / 32;
    constexpr int K2T = H / 32;
    constexpr int NW = (H / 16) / NWAVE;     // channel tiles per wave
    constexpr int E = NB * KNN;
    constexpr int MT1 = E / 16;              // edge tiles
    constexpr int MT2 = NB * 8 / 16;         // slot tiles (8 slots/node; 6,7 dup 0)
    constexpr int K1P = K1T * 32 + 8;        // ushort row strides (16B aligned)
    constexpr int K2P = K2T * 32 + 8;
    constexpr int APL = E * K1P;
    constexpr int HPL = E * K2P;
    constexpr int SM = (2 * APL > 2 * HPL) ? 2 * APL : 2 * HPL;
    static_assert(E % 16 == 0 && E <= NTH, "tile shape");

    __shared__ __align__(16) u16t smem[SM];
    __shared__ int srcs[E];

    const int tid = threadIdx.x;
    const int lane = tid & 63, wv = tid >> 6;
    const int l15 = lane & 15, quad = lane >> 4;
    const int node0 = blockIdx.x * NB;
    const long e0 = (long)node0 * KNN;

    if (tid < E) srcs[tid] = ei[e0 + tid];

    // GEMM1 weights: kt=0 preload (ping-pong streamed in the loop)
    U16 wah[2][NW], wal[2][NW];
#pragma unroll
    for (int t = 0; t < NW; t++) {
        const int fi = ((wv * NW + t) * K1T) * 64 + lane;
        wah[0][t].u = wfa_hi[fi];
        wal[0][t].u = wfa_lo[fi];
    }
    __syncthreads();

    // ---- stage feature planes into LDS
    if constexpr (CX % 8 == 0) {
        constexpr int C8 = CX / 8;
        for (int i = tid; i < E * C8; i += NTH) {
            const int e = i / C8, c = i % C8;
            const size_t sb = (size_t)srcs[e] * CX + c * 8;
            *(uint4*)&smem[e * K1P + c * 8] = *(const uint4*)&xh[sb];
            *(uint4*)&smem[APL + e * K1P + c * 8] = *(const uint4*)&xl[sb];
        }
    }
    if (tid < E) {
        const int e = tid, s = srcs[e], nd = node0 + e / KNN;
#pragma unroll
        for (int d = 0; d < 3; d++) {
            const float sp = pos[3 * s + d];
            if constexpr (CX == 3)
                split_store(&smem[e * K1P + d], &smem[APL + e * K1P + d], sp);
            split_store(&smem[e * K1P + CX + d], &smem[APL + e * K1P + CX + d],
                        sp - pos[3 * nd + d]);
        }
    }
    // zero the K padding
    constexpr int PADA = (CIN + 7) & ~7;
    constexpr int NU4 = (K1P - PADA) / 8;
    for (int i = tid; i < 2 * E; i += NTH) {
        const int pl = (i >= E) ? 1 : 0;
        const int e = i - pl * E;
        u16t* row = &smem[pl * APL + e * K1P];
        for (int k = CIN; k < PADA; k++) row[k] = 0;
        for (int j = 0; j < NU4; j++) *(uint4*)&row[PADA + j * 8] = make_uint4(0, 0, 0, 0);
    }
    __syncthreads();

    // ---- GEMM1: D[channel][edge] = W1^T * A^T (3-term bf16 split)
    f32x4 acc1[NW][MT1];
#pragma unroll
    for (int t = 0; t < NW; t++)
#pragma unroll
        for (int m = 0; m < MT1; m++) acc1[t][m] = (f32x4){0.f, 0.f, 0.f, 0.f};

#pragma unroll
    for (int kt = 0; kt < K1T; kt++) {
        const int cur = kt & 1, nxt = cur ^ 1;
        const int nkt = (kt + 1 < K1T) ? kt + 1 : kt;
#pragma unroll
        for (int t = 0; t < NW; t++) {      // prefetch next kt's weights
            const int fi = ((wv * NW + t) * K1T + nkt) * 64 + lane;
            wah[nxt][t].u = wfa_hi[fi];
            wal[nxt][t].u = wfa_lo[fi];
        }
#pragma unroll
        for (int m = 0; m < MT1; m++) {
            const u16t* p = &smem[(m * 16 + l15) * K1P + kt * 32 + quad * 8];
            U16 dh, dl;
            dh.u = *(const uint4*)p;
            dl.u = *(const uint4*)(p + APL);
#pragma unroll
            for (int t = 0; t < NW; t++) {
                acc1[t][m] = mfma16(wah[cur][t].b, dh.b, acc1[t][m]);
                acc1[t][m] = mfma16(wah[cur][t].b, dl.b, acc1[t][m]);
                acc1[t][m] = mfma16(wal[cur][t].b, dh.b, acc1[t][m]);
            }
        }
    }

    // GEMM2 weights: kt=0 preload (latency covered by epilogue + barrier)
    U16 wbh[2][NW], wbl[2][NW];
#pragma unroll
    for (int t = 0; t < NW; t++) {
        const int fi = ((wv * NW + t) * K2T) * 64 + lane;
        wbh[0][t].u = wfb_hi[fi];
        wbl[0][t].u = wfb_lo[fi];
    }
    __syncthreads();   // all A reads done; smem becomes Hp planes

    // ---- bias + relu + trunc-split, write Hp planes
#pragma unroll
    for (int t = 0; t < NW; t++) {
        const int khb = (wv * NW + t) * 16 + quad * 4;
        const float4 bs = *(const float4*)&ba[khb];
#pragma unroll
        for (int m = 0; m < MT1; m++) {
            const float v0 = fmaxf(acc1[t][m][0] + bs.x, 0.f);
            const float v1 = fmaxf(acc1[t][m][1] + bs.y, 0.f);
            const float v2 = fmaxf(acc1[t][m][2] + bs.z, 0.f);
            const float v3 = fmaxf(acc1[t][m][3] + bs.w, 0.f);
            const unsigned u0 = __float_as_uint(v0), u1 = __float_as_uint(v1);
            const unsigned u2 = __float_as_uint(v2), u3 = __float_as_uint(v3);
            uint2 hw, lw;
            hw.x = top2(u1, u0);
            hw.y = top2(u3, u2);
            const float l0 = v0 - __uint_as_float(u0 & 0xFFFF0000u);
            const float l1 = v1 - __uint_as_float(u1 & 0xFFFF0000u);
            const float l2 = v2 - __uint_as_float(u2 & 0xFFFF0000u);
            const float l3 = v3 - __uint_as_float(u3 & 0xFFFF0000u);
            lw.x = top2(__float_as_uint(l1), __float_as_uint(l0));
            lw.y = top2(__float_as_uint(l3), __float_as_uint(l2));
            u16t* wp = &smem[(m * 16 + l15) * K2P + khb];
            *(uint2*)wp = hw;
            *(uint2*)(wp + HPL) = lw;
        }
    }
    __syncthreads();

    // ---- GEMM2 (swapped): D[slot][channel] = Hp * W2, weights streamed per kt
    int eaddr[MT2];
#pragma unroll
    for (int m = 0; m < MT2; m++) {
        const int slot = m * 16 + l15;
        const int i7 = slot & 7;
        const int e2 = (slot >> 3) * KNN + (i7 < KNN ? i7 : 0);
        eaddr[m] = e2 * K2P + quad * 8;
    }

    f32x4 acc2[NW][MT2];
#pragma unroll
    for (int t = 0; t < NW; t++)
#pragma unroll
        for (int m = 0; m < MT2; m++) acc2[t][m] = (f32x4){0.f, 0.f, 0.f, 0.f};

#pragma unroll
    for (int kt = 0; kt < K2T; kt++) {
        const int cur = kt & 1, nxt = cur ^ 1;
        const int nkt = (kt + 1 < K2T) ? kt + 1 : kt;
#pragma unroll
        for (int t = 0; t < NW; t++) {
            const int fi = ((wv * NW + t) * K2T + nkt) * 64 + lane;
            wbh[nxt][t].u = wfb_hi[fi];
            wbl[nxt][t].u = wfb_lo[fi];
        }
#pragma unroll
        for (int m = 0; m < MT2; m++) {
            const u16t* p = &smem[eaddr[m] + kt * 32];
            U16 dh, dl;
            dh.u = *(const uint4*)p;
            dl.u = *(const uint4*)(p + HPL);
#pragma unroll
            for (int t = 0; t < NW; t++) {
                acc2[t][m] = mfma16(dh.b, wbh[cur][t].b, acc2[t][m]);
                acc2[t][m] = mfma16(dh.b, wbl[cur][t].b, acc2[t][m]);
                acc2[t][m] = mfma16(dl.b, wbh[cur][t].b, acc2[t][m]);
            }
        }
    }

    // ---- segment max: 3 in-lane fmax + 1 cross-quad shfl; direct global store
#pragma unroll
    for (int t = 0; t < NW; t++) {
        const int nb = (wv * NW + t) * 16;
        const float bias = bb[nb + l15];
#pragma unroll
        for (int m = 0; m < MT2; m++) {
            const f32x4 a = acc2[t][m];
            float v = fmaxf(fmaxf(a[0], a[1]), fmaxf(a[2], a[3]));
            v = fmaxf(v, __shfl_xor(v, 16));
            v = fmaxf(v + bias, 0.f);
            if ((quad & 1) == 0) {
                const int node = node0 + 2 * m + (quad >> 1);
                const size_t oidx = (size_t)node * H + nb + l15;
                if constexpr (OUTP) {
                    split_store(&oh[oidx], &ol[oidx], v);
                } else {
                    outf[oidx] = v;
                }
            }
        }
    }
}

// ---------------------------------------------------------------------------
extern "C" void kernel_launch(void* const* d_in, const int* in_sizes, int n_in,
                              void* d_out, int out_size, void* d_ws, size_t ws_size,
                              hipStream_t stream) {
    const float* pos = (const float*)d_in[0];
    const int* ei = (const int*)d_in[1];
    const float* W1a = (const float*)d_in[2];
    const float* b1a = (const float*)d_in[3];
    const float* W1b = (const float*)d_in[4];
    const float* b1b = (const float*)d_in[5];
    const float* W2a = (const float*)d_in[6];
    const float* b2a = (const float*)d_in[7];
    const float* W2b = (const float*)d_in[8];
    const float* b2b = (const float*)d_in[9];
    const float* W3a = (const float*)d_in[10];
    const float* b3a = (const float*)d_in[11];
    const float* W3b = (const float*)d_in[12];
    const float* b3b = (const float*)d_in[13];

    u16t* h1h = (u16t*)d_ws;                       // [NODES][32] hi plane
    u16t* h1l = h1h + (size_t)NODES * 32;          // [NODES][32] lo plane
    u16t* h2h = h1l + (size_t)NODES * 32;          // [NODES][64] hi plane
    u16t* h2l = h2h + (size_t)NODES * 64;          // [NODES][64] lo plane
    uint4* wf = (uint4*)(h2l + (size_t)NODES * 64);
    // fragment uint4 offsets:
    //   W1a h/l @0/128, W1b @256/384, W2a @512/1024, W2b @1536/2048,
    //   W3a @2560/4096 (len 1536), W3b @5632/7680 (len 2048); end 9728

    prep_all<<<20, 256, 0, stream>>>(W1a, W1b, W2a, W2b, W3a, W3b, wf);

    // Layer 1: CX=3 (pos-only), H=32, 2 waves, NB=16
    pnconv_mfma<3, 32, 2, 16, true><<<NODES / 16, 128, 0, stream>>>(
        nullptr, nullptr, pos, ei,
        wf + 0, wf + 128, b1a, wf + 256, wf + 384, b1b,
        nullptr, h1h, h1l);

    // Layer 2: CX=32, H=64, 4 waves (NW=1), NB=16
    pnconv_mfma<32, 64, 4, 16, true><<<NODES / 16, 256, 0, stream>>>(
        h1h, h1l, pos, ei,
        wf + 512, wf + 1024, b2a, wf + 1536, wf + 2048, b2b,
        nullptr, h2h, h2l);

    // Layer 3: CX=64, H=128, 4 waves (NW=2), NB=8, fp32 output
    pnconv_mfma<64, 128, 4, 8, false><<<NODES / 8, 256, 0, stream>>>(
        h2h, h2l, pos, ei,
        wf + 2560, wf + 4096, b3a, wf + 5632, wf + 7680, b3b,
        (float*)d_out, nullptr, nullptr);
}

// Round 7
// 232.968 us; speedup vs baseline: 2.9591x; 1.0878x over previous
//
#include <hip/hip_runtime.h>

#define NODES 100000
#define KNN 6

typedef unsigned short u16t;
typedef __attribute__((ext_vector_type(8))) short bf16x8;
typedef __attribute__((ext_vector_type(4))) float f32x4;
union U16 { uint4 u; bf16x8 b; };

__device__ inline f32x4 mfma16(bf16x8 a, bf16x8 b, f32x4 c) {
    return __builtin_amdgcn_mfma_f32_16x16x32_bf16(a, b, c, 0, 0, 0);
}
// pack top-16 bits of two fp32 words (u0 -> low half, u1 -> high half)
__device__ inline unsigned top2(unsigned u1, unsigned u0) {
    return __builtin_amdgcn_perm(u1, u0, 0x07060302u);
}
__device__ inline u16t bf16_rn(float x) {
    unsigned u = __float_as_uint(x);
    return (u16t)((u + 0x7FFF + ((u >> 16) & 1)) >> 16);
}
__device__ inline float bf16_f(u16t h) {
    return __uint_as_float(((unsigned)h) << 16);
}
// truncation split into hi/lo bf16 planes
__device__ inline void split_store(u16t* hp, u16t* lp, float v) {
    const unsigned u = __float_as_uint(v);
    *hp = (u16t)(u >> 16);
    const float hif = __uint_as_float(u & 0xFFFF0000u);
    *lp = (u16t)(__float_as_uint(v - hif) >> 16);
}

// ---------------------------------------------------------------------------
// Weight prep: W[CIN_][N_] fp32 -> MFMA A-operand fragments (hi/lo bf16).
// Fragment (tile t, k-tile kt): elem[n = t*16 + (lane&15)][k = kt*32 + (lane>>4)*8 + j]
template <int CIN_, int N_>
__device__ void prep_dev(const float* __restrict__ W,
                         uint4* __restrict__ fh, uint4* __restrict__ fl, int idx) {
    constexpr int KT = (CIN_ + 31) / 32;
    constexpr int NTt = N_ / 16;
    if (idx >= NTt * KT * 64) return;
    const int lane = idx & 63;
    const int fk = idx >> 6;
    const int kt = fk % KT, t = fk / KT;
    const int n = t * 16 + (lane & 15);
    const int kbase = kt * 32 + (lane >> 4) * 8;
    unsigned h[4], l[4];
    for (int p = 0; p < 4; p++) {
        u16t hh[2], ll[2];
        for (int q = 0; q < 2; q++) {
            const int c = kbase + 2 * p + q;
            const float w = (c < CIN_) ? W[(size_t)c * N_ + n] : 0.f;
            const u16t hi = bf16_rn(w);
            hh[q] = hi;
            ll[q] = bf16_rn(w - bf16_f(hi));
        }
        h[p] = (unsigned)hh[0] | ((unsigned)hh[1] << 16);
        l[p] = (unsigned)ll[0] | ((unsigned)ll[1] << 16);
    }
    fh[idx] = make_uint4(h[0], h[1], h[2], h[3]);
    fl[idx] = make_uint4(l[0], l[1], l[2], l[3]);
}

__global__ void prep_all(const float* W1a, const float* W1b,
                         const float* W2a, const float* W2b,
                         const float* W3a, const float* W3b, uint4* wf) {
    const int b = blockIdx.x, t = threadIdx.x;
    if (b == 0)      prep_dev<6, 32>(W1a, wf + 0, wf + 128, t);
    else if (b == 1) prep_dev<32, 32>(W1b, wf + 256, wf + 384, t);
    else if (b < 4)  prep_dev<35, 64>(W2a, wf + 512, wf + 1024, (b - 2) * 256 + t);
    else if (b < 6)  prep_dev<64, 64>(W2b, wf + 1536, wf + 2048, (b - 4) * 256 + t);
    else if (b < 12) prep_dev<67, 128>(W3a, wf + 2560, wf + 4096, (b - 6) * 256 + t);
    else             prep_dev<128, 128>(W3b, wf + 5632, wf + 7680, (b - 12) * 256 + t);
}

// ---------------------------------------------------------------------------
// MFMA PointNetConv layer (all 3 layers). Features as separate hi/lo bf16 planes.
// CX==3: layer-1 mode (features = pos, staged directly; no x-gather).
// GEMM1: A = weights (regs, kt-streamed), B = data (LDS)   rows=channels, cols=edges
// GEMM2: A = data (LDS), B = weights (regs, kt-streamed)   rows=slots,    cols=channels
//
// GEMM2 slot permutation (no padding; E = 48*g tiles of 16):
//   slot s (tile m, w = s&15, quad q = w>>2, reg r = w&3) maps to
//   edge = node*6 + i,  node = (m/3)*8 + 2q + (r>>1),  i = (m%3)*2 + (r&1).
// With this map a node's 6 edges live in ONE lane across the m-triple's
// reg-pairs -> segment max is 6 in-lane fmax, no shuffles, no predication.
template <int CX, int H, int NWAVE, int NB, bool OUTP>
__global__ __launch_bounds__(NWAVE * 64, 4) void pnconv_mfma(
    const u16t* __restrict__ xh, const u16t* __restrict__ xl,
    const float* __restrict__ pos, const int* __restrict__ ei,
    const uint4* __restrict__ wfa_hi, const uint4* __restrict__ wfa_lo,
    const float* __restrict__ ba,
    const uint4* __restrict__ wfb_hi, const uint4* __restrict__ wfb_lo,
    const float* __restrict__ bb,
    float* __restrict__ outf, u16t* __restrict__ oh, u16t* __restrict__ ol)
{
    constexpr int NTH = NWAVE * 64;
    constexpr int CIN = CX + 3;
    constexpr int K1T = (CIN + 31) / 32;
    constexpr int K2T = H / 32;
    constexpr int NW = (H / 16) / NWAVE;     // channel tiles per wave
    constexpr int E = NB * KNN;
    constexpr int MT1 = E / 16;              // edge tiles (GEMM1 N)
    constexpr int MT2 = E / 16;              // slot tiles (GEMM2 M), unpadded
    constexpr int K1P = K1T * 32 + 8;        // ushort row strides (16B aligned)
    constexpr int K2P = K2T * 32 + 8;
    constexpr int APL = E * K1P;
    constexpr int HPL = E * K2P;
    constexpr int SM = (2 * APL > 2 * HPL) ? 2 * APL : 2 * HPL;
    static_assert(E % 48 == 0 && E <= NTH, "tile shape");
    static_assert(MT2 % 3 == 0, "slot perm needs m-triples");

    __shared__ __align__(16) u16t smem[SM];
    __shared__ int srcs[E];

    const int tid = threadIdx.x;
    const int lane = tid & 63, wv = tid >> 6;
    const int l15 = lane & 15, quad = lane >> 4;
    const int node0 = blockIdx.x * NB;
    const long e0 = (long)node0 * KNN;

    if (tid < E) srcs[tid] = ei[e0 + tid];

    // GEMM1 weights: kt=0 preload (ping-pong streamed in the loop)
    U16 wah[2][NW], wal[2][NW];
#pragma unroll
    for (int t = 0; t < NW; t++) {
        const int fi = ((wv * NW + t) * K1T) * 64 + lane;
        wah[0][t].u = wfa_hi[fi];
        wal[0][t].u = wfa_lo[fi];
    }
    __syncthreads();

    // ---- stage feature planes into LDS (chunk-rotated: bank-conflict-free)
    if constexpr (CX % 8 == 0) {
        constexpr int C8 = CX / 8;
        for (int i = tid; i < E * C8; i += NTH) {
            const int e = i / C8, c0 = i % C8;
            const int c = (c0 + e) & (C8 - 1);   // rotate lane->chunk within the row
            const size_t sb = (size_t)srcs[e] * CX + c * 8;
            *(uint4*)&smem[e * K1P + c * 8] = *(const uint4*)&xh[sb];
            *(uint4*)&smem[APL + e * K1P + c * 8] = *(const uint4*)&xl[sb];
        }
    }
    for (int i = tid; i < E * 3; i += NTH) {
        const int e = i / 3, d = i - 3 * (i / 3);
        const int s = srcs[e], nd = node0 + e / KNN;
        const float sp = pos[3 * s + d];
        if constexpr (CX == 3)
            split_store(&smem[e * K1P + d], &smem[APL + e * K1P + d], sp);
        split_store(&smem[e * K1P + CX + d], &smem[APL + e * K1P + CX + d],
                    sp - pos[3 * nd + d]);
    }
    // zero the K padding
    constexpr int PADA = (CIN + 7) & ~7;
    constexpr int NU4 = (K1P - PADA) / 8;
    for (int i = tid; i < 2 * E; i += NTH) {
        const int pl = (i >= E) ? 1 : 0;
        const int e = i - pl * E;
        u16t* row = &smem[pl * APL + e * K1P];
        for (int k = CIN; k < PADA; k++) row[k] = 0;
        for (int j = 0; j < NU4; j++) *(uint4*)&row[PADA + j * 8] = make_uint4(0, 0, 0, 0);
    }
    __syncthreads();

    // ---- GEMM1: D[channel][edge] = W1^T * A^T (3-term bf16 split)
    f32x4 acc1[NW][MT1];
#pragma unroll
    for (int t = 0; t < NW; t++)
#pragma unroll
        for (int m = 0; m < MT1; m++) acc1[t][m] = (f32x4){0.f, 0.f, 0.f, 0.f};

#pragma unroll
    for (int kt = 0; kt < K1T; kt++) {
        const int cur = kt & 1, nxt = cur ^ 1;
        const int nkt = (kt + 1 < K1T) ? kt + 1 : kt;
#pragma unroll
        for (int t = 0; t < NW; t++) {      // prefetch next kt's weights
            const int fi = ((wv * NW + t) * K1T + nkt) * 64 + lane;
            wah[nxt][t].u = wfa_hi[fi];
            wal[nxt][t].u = wfa_lo[fi];
        }
#pragma unroll
        for (int m = 0; m < MT1; m++) {
            const u16t* p = &smem[(m * 16 + l15) * K1P + kt * 32 + quad * 8];
            U16 dh, dl;
            dh.u = *(const uint4*)p;
            dl.u = *(const uint4*)(p + APL);
#pragma unroll
            for (int t = 0; t < NW; t++) {
                acc1[t][m] = mfma16(wah[cur][t].b, dh.b, acc1[t][m]);
                acc1[t][m] = mfma16(wah[cur][t].b, dl.b, acc1[t][m]);
                acc1[t][m] = mfma16(wal[cur][t].b, dh.b, acc1[t][m]);
            }
        }
    }

    // GEMM2 weights: kt=0 preload (latency covered by epilogue + barrier)
    U16 wbh[2][NW], wbl[2][NW];
#pragma unroll
    for (int t = 0; t < NW; t++) {
        const int fi = ((wv * NW + t) * K2T) * 64 + lane;
        wbh[0][t].u = wfb_hi[fi];
        wbl[0][t].u = wfb_lo[fi];
    }
    __syncthreads();   // all A reads done; smem becomes Hp planes

    // ---- bias + relu + trunc-split, write Hp planes
#pragma unroll
    for (int t = 0; t < NW; t++) {
        const int khb = (wv * NW + t) * 16 + quad * 4;
        const float4 bs = *(const float4*)&ba[khb];
#pragma unroll
        for (int m = 0; m < MT1; m++) {
            const float v0 = fmaxf(acc1[t][m][0] + bs.x, 0.f);
            const float v1 = fmaxf(acc1[t][m][1] + bs.y, 0.f);
            const float v2 = fmaxf(acc1[t][m][2] + bs.z, 0.f);
            const float v3 = fmaxf(acc1[t][m][3] + bs.w, 0.f);
            const unsigned u0 = __float_as_uint(v0), u1 = __float_as_uint(v1);
            const unsigned u2 = __float_as_uint(v2), u3 = __float_as_uint(v3);
            uint2 hw, lw;
            hw.x = top2(u1, u0);
            hw.y = top2(u3, u2);
            const float l0 = v0 - __uint_as_float(u0 & 0xFFFF0000u);
            const float l1 = v1 - __uint_as_float(u1 & 0xFFFF0000u);
            const float l2 = v2 - __uint_as_float(u2 & 0xFFFF0000u);
            const float l3 = v3 - __uint_as_float(u3 & 0xFFFF0000u);
            lw.x = top2(__float_as_uint(l1), __float_as_uint(l0));
            lw.y = top2(__float_as_uint(l3), __float_as_uint(l2));
            u16t* wp = &smem[(m * 16 + l15) * K2P + khb];
            *(uint2*)wp = hw;
            *(uint2*)(wp + HPL) = lw;
        }
    }
    __syncthreads();

    // ---- GEMM2 (swapped): D[slot][channel] = Hp * W2, weights streamed per kt
    int eaddr[MT2];
#pragma unroll
    for (int m = 0; m < MT2; m++) {
        const int nd_s = (m / 3) * 8 + 2 * (l15 >> 2) + ((l15 >> 1) & 1);
        const int i_s = (m % 3) * 2 + (l15 & 1);
        eaddr[m] = (nd_s * KNN + i_s) * K2P + quad * 8;
    }

    f32x4 acc2[NW][MT2];
#pragma unroll
    for (int t = 0; t < NW; t++)
#pragma unroll
        for (int m = 0; m < MT2; m++) acc2[t][m] = (f32x4){0.f, 0.f, 0.f, 0.f};

#pragma unroll
    for (int kt = 0; kt < K2T; kt++) {
        const int cur = kt & 1, nxt = cur ^ 1;
        const int nkt = (kt + 1 < K2T) ? kt + 1 : kt;
#pragma unroll
        for (int t = 0; t < NW; t++) {
            const int fi = ((wv * NW + t) * K2T + nkt) * 64 + lane;
            wbh[nxt][t].u = wfb_hi[fi];
            wbl[nxt][t].u = wfb_lo[fi];
        }
#pragma unroll
        for (int m = 0; m < MT2; m++) {
            const u16t* p = &smem[eaddr[m] + kt * 32];
            U16 dh, dl;
            dh.u = *(const uint4*)p;
            dl.u = *(const uint4*)(p + HPL);
#pragma unroll
            for (int t = 0; t < NW; t++) {
                acc2[t][m] = mfma16(dh.b, wbh[cur][t].b, acc2[t][m]);
                acc2[t][m] = mfma16(dh.b, wbl[cur][t].b, acc2[t][m]);
                acc2[t][m] = mfma16(dl.b, wbh[cur][t].b, acc2[t][m]);
            }
        }
    }

    // ---- segment max: fully in-lane (slot perm), 2 nodes per lane per m-triple
#pragma unroll
    for (int t = 0; t < NW; t++) {
        const int nb = (wv * NW + t) * 16;
        const float bias = bb[nb + l15];
#pragma unroll
        for (int g = 0; g < MT2 / 3; g++) {
#pragma unroll
            for (int rp = 0; rp < 2; rp++) {
                float v = fmaxf(
                    fmaxf(fmaxf(acc2[t][3 * g + 0][2 * rp], acc2[t][3 * g + 0][2 * rp + 1]),
                          fmaxf(acc2[t][3 * g + 1][2 * rp], acc2[t][3 * g + 1][2 * rp + 1])),
                    fmaxf(acc2[t][3 * g + 2][2 * rp], acc2[t][3 * g + 2][2 * rp + 1]));
                v = fmaxf(v + bias, 0.f);
                const int node = node0 + g * 8 + 2 * quad + rp;
                const size_t oidx = (size_t)node * H + nb + l15;
                if constexpr (OUTP) {
                    split_store(&oh[oidx], &ol[oidx], v);
                } else {
                    outf[oidx] = v;
                }
            }
        }
    }
}

// ---------------------------------------------------------------------------
extern "C" void kernel_launch(void* const* d_in, const int* in_sizes, int n_in,
                              void* d_out, int out_size, void* d_ws, size_t ws_size,
                              hipStream_t stream) {
    const float* pos = (const float*)d_in[0];
    const int* ei = (const int*)d_in[1];
    const float* W1a = (const float*)d_in[2];
    const float* b1a = (const float*)d_in[3];
    const float* W1b = (const float*)d_in[4];
    const float* b1b = (const float*)d_in[5];
    const float* W2a = (const float*)d_in[6];
    const float* b2a = (const float*)d_in[7];
    const float* W2b = (const float*)d_in[8];
    const float* b2b = (const float*)d_in[9];
    const float* W3a = (const float*)d_in[10];
    const float* b3a = (const float*)d_in[11];
    const float* W3b = (const float*)d_in[12];
    const float* b3b = (const float*)d_in[13];

    u16t* h1h = (u16t*)d_ws;                       // [NODES][32] hi plane
    u16t* h1l = h1h + (size_t)NODES * 32;          // [NODES][32] lo plane
    u16t* h2h = h1l + (size_t)NODES * 32;          // [NODES][64] hi plane
    u16t* h2l = h2h + (size_t)NODES * 64;          // [NODES][64] lo plane
    uint4* wf = (uint4*)(h2l + (size_t)NODES * 64);
    // fragment uint4 offsets:
    //   W1a h/l @0/128, W1b @256/384, W2a @512/1024, W2b @1536/2048,
    //   W3a @2560/4096 (len 1536), W3b @5632/7680 (len 2048); end 9728

    prep_all<<<20, 256, 0, stream>>>(W1a, W1b, W2a, W2b, W3a, W3b, wf);

    // Layer 1: CX=3 (pos-only), H=32, 2 waves, NB=16
    pnconv_mfma<3, 32, 2, 16, true><<<NODES / 16, 128, 0, stream>>>(
        nullptr, nullptr, pos, ei,
        wf + 0, wf + 128, b1a, wf + 256, wf + 384, b1b,
        nullptr, h1h, h1l);

    // Layer 2: CX=32, H=64, 4 waves (NW=1), NB=16
    pnconv_mfma<32, 64, 4, 16, true><<<NODES / 16, 256, 0, stream>>>(
        h1h, h1l, pos, ei,
        wf + 512, wf + 1024, b2a, wf + 1536, wf + 2048, b2b,
        nullptr, h2h, h2l);

    // Layer 3: CX=64, H=128, 4 waves (NW=2), NB=8, fp32 output
    pnconv_mfma<64, 128, 4, 8, false><<<NODES / 8, 256, 0, stream>>>(
        h2h, h2l, pos, ei,
        wf + 2560, wf + 4096, b3a, wf + 5632, wf + 7680, b3b,
        (float*)d_out, nullptr, nullptr);
}